// Round 6
// baseline (249.343 us; speedup 1.0000x reference)
//
#include <hip/hip_runtime.h>

#define V 128000
#define V4 (V / 4)
#define NCHUNK (V / 16)      // 8000 chunk-max entries (16 elems each)
#define NROWS 256
#define NSLICE 8
#define SL4 (V4 / NSLICE)    // 4000 float4 per slice
#define SLC (NCHUNK / NSLICE)// 1000 chunks per slice
#define W 200
#define VW (V / 32)          // 4000 words of seen-bitmask
#define CAP 4096             // survivor capacity
#define CAPM 8192            // mono-kernel capacity
#define TINYF 1.17549435e-38f

// ---- d_ws layout (needs >= 16 MiB) ----
#define WS_CMAX   0u          // u16[256][8000]            = 4,096,000
#define WS_BMAX   4104192u    // float[256][8]             = 8,192  (starts 4,096,000 rounded up)
#define WS_KTH    4112384u    // float[256]
#define WS_G      4113408u    // int[256]
#define WS_P0     4114432u    // int[256]
#define WS_SVAL   4194304u    // float[256][4096]          = 4 MiB
#define WS_SIDX   8388608u    // int[256][4096]            = 4 MiB
#define WS_PE     12582912u   // float[256][4096]          = 4 MiB
#define WS_NEED   16777216u

typedef float vfloat4 __attribute__((ext_vector_type(4)));

__device__ __forceinline__ unsigned int fkey(float x) {
  unsigned int u = __float_as_uint(x);
  return (u & 0x80000000u) ? ~u : (u | 0x80000000u);
}

// ---- jax threefry2x32, partitionable: counter=(0,t), key=(0,42), fold=xor ----
__device__ __forceinline__ unsigned int tf_bits(unsigned int t) {
  const unsigned int k0 = 0u, k1 = 42u;
  const unsigned int ks2 = k0 ^ k1 ^ 0x1BD11BDAu;
  unsigned int x0 = 0u + k0, x1 = t + k1;
  const unsigned int ksArr[3] = {k0, k1, ks2};
  const int RA[4] = {13, 15, 26, 6};
  const int RB[4] = {17, 29, 16, 24};
#pragma unroll
  for (int i = 0; i < 5; ++i) {
#pragma unroll
    for (int j = 0; j < 4; ++j) {
      int r = (i & 1) ? RB[j] : RA[j];
      x0 += x1;
      x1 = (x1 << r) | (x1 >> (32 - r));
      x1 ^= x0;
    }
    x0 += ksArr[(i + 1) % 3];
    x1 += ksArr[(i + 2) % 3] + (unsigned int)(i + 1);
  }
  return x0 ^ x1;
}

__device__ __forceinline__ float xform(float x, bool seen, float rp, float irp,
                                        float itemp) {
  if (seen) x = (x > 0.0f) ? x * irp : x * rp;
  return x * itemp;
}

// ================== Kernel A: transform + chunk-max + slice-max ==================
__global__ __launch_bounds__(256) void kA_chunkmax(
    const float* __restrict__ logits, const int* __restrict__ toks,
    const float* __restrict__ temps, const float* __restrict__ rps,
    unsigned short* __restrict__ ws_cmax, float* __restrict__ ws_bmax) {
  __shared__ unsigned int s_seen[VW];
  __shared__ float s_red[4];
  const int row = blockIdx.x >> 3;
  const int slice = blockIdx.x & 7;
  const int tid = threadIdx.x;
  const int lane = tid & 63;
  const int wid = tid >> 6;
  const float rp = rps[row];
  const float irp = 1.0f / rp;
  const float itemp = 1.0f / temps[row];
  const size_t base = (size_t)row * V;
  const float4* __restrict__ lg4 = reinterpret_cast<const float4*>(logits + base);

  for (int i = tid; i < VW; i += 256) s_seen[i] = 0u;
  __syncthreads();
  for (int i = tid; i < W; i += 256) {
    int tok = toks[row * W + i];
    if (tok >= 0 && tok < V) atomicOr(&s_seen[tok >> 5], 1u << (tok & 31));
  }
  __syncthreads();

  float lmax = -INFINITY;
  const int q0 = slice * SL4;
  for (int qi = tid; qi < SL4; qi += 256) {
    const int q = q0 + qi;
    float4 x4 = lg4[q];
    float xs[4] = {x4.x, x4.y, x4.z, x4.w};
    const int j0 = q * 4;
    const int sh = j0 & 31;
    unsigned long long ww = (unsigned long long)s_seen[j0 >> 5] |
                            ((unsigned long long)s_seen[(j0 + 3) >> 5] << 32);
    unsigned int kmax = 0u;
#pragma unroll
    for (int e = 0; e < 4; ++e) {
      float x = xform(xs[e], (ww >> (sh + e)) & 1ull, rp, irp, itemp);
      lmax = fmaxf(lmax, x);
      unsigned int ky = fkey(x);
      kmax = kmax > ky ? kmax : ky;
    }
    unsigned int o;
    o = __shfl_xor(kmax, 1); kmax = kmax > o ? kmax : o;
    o = __shfl_xor(kmax, 2); kmax = kmax > o ? kmax : o;
    if ((lane & 3) == 0) ws_cmax[row * NCHUNK + (q >> 2)] = (unsigned short)(kmax >> 16);
  }
#pragma unroll
  for (int d = 32; d > 0; d >>= 1) lmax = fmaxf(lmax, __shfl_xor(lmax, d));
  if (lane == 0) s_red[wid] = lmax;
  __syncthreads();
  if (tid == 0) {
    float mm = fmaxf(fmaxf(s_red[0], s_red[1]), fmaxf(s_red[2], s_red[3]));
    ws_bmax[row * NSLICE + slice] = mm;
  }
}

// ================== Kernel B: select + gather + sort + top-p + sample ==================
__global__ __launch_bounds__(1024, 1) void kB_select(
    const float* __restrict__ logits, const int* __restrict__ toks,
    const float* __restrict__ temps, const float* __restrict__ topps,
    const int* __restrict__ topks, const float* __restrict__ rps,
    const unsigned short* __restrict__ ws_cmax, const float* __restrict__ ws_bmax,
    float* __restrict__ ws_kth, int* __restrict__ ws_G, int* __restrict__ ws_p0,
    float* __restrict__ ws_sval, int* __restrict__ ws_sidx, float* __restrict__ ws_pe,
    float* __restrict__ out_ids) {
  __shared__ unsigned int s_seen[VW];         // 16000 B
  __shared__ unsigned short s_cmax16[NCHUNK]; // 16000 B
  __shared__ int s_hist[4096];                // 16384 B
  __shared__ float s_sval[CAP];               // 16384 B
  __shared__ int s_sidx[CAP];                 // 16384 B
  __shared__ float s_e[CAP];                  // 16384 B
  __shared__ unsigned char s_keep[CAP];       // 4096 B
  __shared__ float s_wredf[16];
  __shared__ int s_wredi[16];
  __shared__ float s_m, s_denom, s_denom2;
  __shared__ int s_b0, s_cnt, s_p0s;

  const int row = blockIdx.x;
  const int tid = threadIdx.x;
  const int lane = tid & 63;
  const int wid = tid >> 6;
  const float rp = rps[row];
  const float irp = 1.0f / rp;
  const float itemp = 1.0f / temps[row];
  const float topp = topps[row];
  const int k = topks[row];
  const size_t base = (size_t)row * V;
  const float4* __restrict__ lg4 = reinterpret_cast<const float4*>(logits + base);

  // seen bitmask + cmax->LDS + zero hist
  for (int i = tid; i < VW; i += 1024) s_seen[i] = 0u;
  for (int i = tid; i < 4096; i += 1024) s_hist[i] = 0;
  {
    const unsigned int* cm32 = reinterpret_cast<const unsigned int*>(ws_cmax + row * NCHUNK);
    unsigned int* sc32 = reinterpret_cast<unsigned int*>(s_cmax16);
    for (int i = tid; i < NCHUNK / 2; i += 1024) sc32[i] = cm32[i];
  }
  __syncthreads();
  for (int i = tid; i < W; i += 1024) {
    int tok = toks[row * W + i];
    if (tok >= 0 && tok < V) atomicOr(&s_seen[tok >> 5], 1u << (tok & 31));
  }
  __syncthreads();

  // chunk-max histogram
  for (int i = tid; i < NCHUNK; i += 1024)
    atomicAdd(&s_hist[s_cmax16[i] >> 4], 1);
  __syncthreads();

  // bucket select (wave 0); m (wave 1)
  if (wid == 1 && lane == 0) {
    float mm = ws_bmax[row * NSLICE];
    for (int i = 1; i < NSLICE; ++i) mm = fmaxf(mm, ws_bmax[row * NSLICE + i]);
    s_m = mm;
  }
  if (wid == 0) {
    int sm = 0;
    const int bb = lane * 64;
    for (int i = 0; i < 64; ++i) sm += s_hist[bb + i];
    int sfx = sm;
#pragma unroll
    for (int d = 1; d < 64; d <<= 1) {
      int t = __shfl_down(sfx, d);
      if (lane + d < 64) sfx += t;
    }
    unsigned long long mk = __ballot(sfx >= k);
    const int cstar = 63 - __builtin_clzll(mk);
    const int above = __shfl(sfx, cstar) - __shfl(sm, cstar);
    int h = s_hist[cstar * 64 + lane];
    int sfx2 = h;
#pragma unroll
    for (int d = 1; d < 64; d <<= 1) {
      int t = __shfl_down(sfx2, d);
      if (lane + d < 64) sfx2 += t;
    }
    unsigned long long mk2 = __ballot(above + sfx2 >= k);
    const int boff = 63 - __builtin_clzll(mk2);
    if (lane == 0) { s_b0 = cstar * 64 + boff; s_cnt = 0; }
  }
  __syncthreads();
  const int b0 = s_b0;

  // gather candidates (chunk filter + wave-agg push)
  const unsigned int fk0 = ((unsigned int)b0) << 20;
  const int c16 = b0 << 4;
  for (int qb = 0; qb < V4; qb += 1024) {
    const int q = qb + tid;
    const bool act = (q < V4) && ((int)s_cmax16[q >> 2] >= c16);
    float xs[4];
    bool pr[4] = {false, false, false, false};
    const int j0 = q * 4;
    if (act) {
      float4 x4 = lg4[q];
      float raw[4] = {x4.x, x4.y, x4.z, x4.w};
      const int sh = j0 & 31;
      unsigned long long ww = (unsigned long long)s_seen[j0 >> 5] |
                              ((unsigned long long)s_seen[(j0 + 3) >> 5] << 32);
#pragma unroll
      for (int e = 0; e < 4; ++e) {
        xs[e] = xform(raw[e], (ww >> (sh + e)) & 1ull, rp, irp, itemp);
        pr[e] = (fkey(xs[e]) >= fk0);
      }
    }
#pragma unroll
    for (int e = 0; e < 4; ++e) {
      unsigned long long mask = __ballot(pr[e]);
      if (!mask) continue;
      int basep = 0;
      if (lane == 0) basep = atomicAdd(&s_cnt, __popcll(mask));
      basep = __shfl(basep, 0);
      if (pr[e]) {
        int pos = basep + __popcll(mask & ((1ull << lane) - 1ull));
        if (pos < CAP) { s_sval[pos] = xs[e]; s_sidx[pos] = j0 + e; }
      }
    }
  }
  __syncthreads();
  int G = s_cnt;
  if (G > CAP) G = CAP;

  // bitonic sort ascending by (value, index)
  int np2 = 2;
  while (np2 < G) np2 <<= 1;
  for (int i = G + tid; i < np2; i += 1024) {
    s_sval[i] = INFINITY;
    s_sidx[i] = 0x7FFFFFFF;
  }
  __syncthreads();
  for (int size = 2; size <= np2; size <<= 1) {
    for (int stride = size >> 1; stride > 0; stride >>= 1) {
      for (int t2 = tid; t2 < (np2 >> 1); t2 += 1024) {
        int pos = 2 * t2 - (t2 & (stride - 1));
        int qq = pos + stride;
        bool up = ((pos & size) == 0);
        float v1 = s_sval[pos], v2 = s_sval[qq];
        int i1 = s_sidx[pos], i2 = s_sidx[qq];
        bool gt = (v1 > v2) || (v1 == v2 && i1 > i2);
        if (gt == up) {
          s_sval[pos] = v2; s_sval[qq] = v1;
          s_sidx[pos] = i2; s_sidx[qq] = i1;
        }
      }
      __syncthreads();
    }
  }

  const int kk = k > G ? G : k;
  const float kth = s_sval[G - kk];
  const float m = s_m;
  for (int i = tid; i < G; i += 1024) {
    if (s_sval[i] >= kth && (i == 0 || s_sval[i - 1] < kth)) s_p0s = i;
  }
  __syncthreads();
  const int p0 = s_p0s;

  // softmax denom over survivors
  float part = 0.0f;
  for (int i = p0 + tid; i < G; i += 1024) {
    float e = expf(s_sval[i] - m);
    s_e[i] = e;
    part += e;
  }
#pragma unroll
  for (int d = 32; d > 0; d >>= 1) part += __shfl_xor(part, d);
  if (lane == 0) s_wredf[wid] = part;
  __syncthreads();
  if (tid == 0) {
    float s = 0.0f;
    for (int i = 0; i < 16; ++i) s += s_wredf[i];
    s_denom = s;
  }
  __syncthreads();
  const float denom = s_denom;

  // sequential cumsum + top-p mask
  if (tid == 0) {
    const float cut = 1.0f - topp;
    float cs = 0.0f;
    int i = p0;
    for (; i + 8 <= G; i += 8) {
      float v0 = s_e[i], v1 = s_e[i + 1], v2 = s_e[i + 2], v3 = s_e[i + 3];
      float v4 = s_e[i + 4], v5 = s_e[i + 5], v6 = s_e[i + 6], v7 = s_e[i + 7];
      float d0 = v0 / denom, d1 = v1 / denom, d2 = v2 / denom, d3 = v3 / denom;
      float d4 = v4 / denom, d5 = v5 / denom, d6 = v6 / denom, d7 = v7 / denom;
      cs += d0; s_keep[i] = (cs <= cut) ? 0 : 1;
      cs += d1; s_keep[i + 1] = (cs <= cut) ? 0 : 1;
      cs += d2; s_keep[i + 2] = (cs <= cut) ? 0 : 1;
      cs += d3; s_keep[i + 3] = (cs <= cut) ? 0 : 1;
      cs += d4; s_keep[i + 4] = (cs <= cut) ? 0 : 1;
      cs += d5; s_keep[i + 5] = (cs <= cut) ? 0 : 1;
      cs += d6; s_keep[i + 6] = (cs <= cut) ? 0 : 1;
      cs += d7; s_keep[i + 7] = (cs <= cut) ? 0 : 1;
    }
    for (; i < G; ++i) {
      cs += s_e[i] / denom;
      s_keep[i] = (cs <= cut) ? 0 : 1;
    }
    s_keep[G - 1] = 1;
  }
  __syncthreads();

  // final denom over kept
  part = 0.0f;
  for (int i = p0 + tid; i < G; i += 1024)
    if (s_keep[i]) part += s_e[i];
#pragma unroll
  for (int d = 32; d > 0; d >>= 1) part += __shfl_xor(part, d);
  if (lane == 0) s_wredf[wid] = part;
  __syncthreads();
  if (tid == 0) {
    float s = 0.0f;
    for (int i = 0; i < 16; ++i) s += s_wredf[i];
    s_denom2 = s;
  }
  __syncthreads();
  const float denom2 = s_denom2;

  for (int i = p0 + tid; i < G; i += 1024)
    s_e[i] = s_keep[i] ? (s_e[i] / denom2) : 0.0f;
  __syncthreads();

  // Gumbel argmax over kept survivors
  float bs = -INFINITY;
  int bi = 0x7FFFFFFF;
  for (int i = p0 + tid; i < G; i += 1024) {
    if (!s_keep[i]) continue;
    int j = s_sidx[i];
    unsigned int t = (unsigned int)(row * V) + (unsigned int)j;
    unsigned int bb = tf_bits(t);
    float u = __uint_as_float((bb >> 9) | 0x3f800000u) - 1.0f;
    if (u < TINYF) u = TINYF;
    float g = -logf(-logf(u));
    float sc = s_sval[i] + g;
    if (sc > bs || (sc == bs && j < bi)) { bs = sc; bi = j; }
  }

  // dump survivor table + meta for kernel C
  for (int i = p0 + tid; i < G; i += 1024) {
    ws_sval[row * CAP + i] = s_sval[i];
    ws_sidx[row * CAP + i] = s_sidx[i];
    ws_pe[row * CAP + i] = s_e[i];
  }
  if (tid == 0) {
    ws_kth[row] = kth;
    ws_G[row] = G;
    ws_p0[row] = p0;
  }

#pragma unroll
  for (int d = 32; d > 0; d >>= 1) {
    float ov = __shfl_down(bs, d);
    int oi = __shfl_down(bi, d);
    if (ov > bs || (ov == bs && oi < bi)) { bs = ov; bi = oi; }
  }
  if (lane == 0) { s_wredf[wid] = bs; s_wredi[wid] = bi; }
  __syncthreads();
  if (tid == 0) {
    float bb = s_wredf[0];
    int bj = s_wredi[0];
    for (int i = 1; i < 16; ++i) {
      if (s_wredf[i] > bb || (s_wredf[i] == bb && s_wredi[i] < bj)) {
        bb = s_wredf[i];
        bj = s_wredi[i];
      }
    }
    out_ids[row] = (float)bj;
  }
}

// ================== Kernel C: write probs ==================
__global__ __launch_bounds__(256) void kC_probs(
    const float* __restrict__ logits, const int* __restrict__ toks,
    const float* __restrict__ temps, const float* __restrict__ rps,
    const unsigned short* __restrict__ ws_cmax, const float* __restrict__ ws_kth,
    const int* __restrict__ ws_G, const int* __restrict__ ws_p0,
    const float* __restrict__ ws_sval, const int* __restrict__ ws_sidx,
    const float* __restrict__ ws_pe, float* __restrict__ probs) {
  __shared__ unsigned int s_seen[VW];
  __shared__ unsigned short s_cm[SLC];
  const int row = blockIdx.x >> 3;
  const int slice = blockIdx.x & 7;
  const int tid = threadIdx.x;
  const float rp = rps[row];
  const float irp = 1.0f / rp;
  const float itemp = 1.0f / temps[row];
  const size_t base = (size_t)row * V;
  const float4* __restrict__ lg4 = reinterpret_cast<const float4*>(logits + base);
  vfloat4* __restrict__ pr4 = reinterpret_cast<vfloat4*>(probs + base);
  const float kth = ws_kth[row];
  const int G = ws_G[row];
  const int p0 = ws_p0[row];
  const float* __restrict__ g_sval = ws_sval + row * CAP;
  const int* __restrict__ g_sidx = ws_sidx + row * CAP;
  const float* __restrict__ g_pe = ws_pe + row * CAP;
  const int k16 = (int)(fkey(kth) >> 16);

  for (int i = tid; i < VW; i += 256) s_seen[i] = 0u;
  for (int i = tid; i < SLC; i += 256) s_cm[i] = ws_cmax[row * NCHUNK + slice * SLC + i];
  __syncthreads();
  for (int i = tid; i < W; i += 256) {
    int tok = toks[row * W + i];
    if (tok >= 0 && tok < V) atomicOr(&s_seen[tok >> 5], 1u << (tok & 31));
  }
  __syncthreads();

  const int q0 = slice * SL4;
  for (int qi = tid; qi < SL4; qi += 256) {
    const int q = q0 + qi;
    vfloat4 o = (vfloat4){0.0f, 0.0f, 0.0f, 0.0f};
    if ((int)s_cm[(q >> 2) - slice * SLC] >= k16) {
      float4 x4 = lg4[q];
      float raw[4] = {x4.x, x4.y, x4.z, x4.w};
      float os[4];
      const int j0 = q * 4;
      const int sh = j0 & 31;
      unsigned long long ww = (unsigned long long)s_seen[j0 >> 5] |
                              ((unsigned long long)s_seen[(j0 + 3) >> 5] << 32);
#pragma unroll
      for (int e = 0; e < 4; ++e) {
        float x = xform(raw[e], (ww >> (sh + e)) & 1ull, rp, irp, itemp);
        float pr = 0.0f;
        if (x >= kth) {
          int j = j0 + e;
          int lo = p0, hi = G;
          while (lo < hi) {
            int mid = (lo + hi) >> 1;
            float v = g_sval[mid];
            int id = g_sidx[mid];
            if (v < x || (v == x && id < j)) lo = mid + 1; else hi = mid;
          }
          pr = g_pe[lo];
        }
        os[e] = pr;
      }
      o.x = os[0]; o.y = os[1]; o.z = os[2]; o.w = os[3];
    }
    __builtin_nontemporal_store(o, &pr4[q]);
  }
}

// ================== Fallback: round-5 monolithic kernel ==================
__global__ __launch_bounds__(1024, 1) void sampler_mono(
    const float* __restrict__ logits, const int* __restrict__ toks,
    const float* __restrict__ temps, const float* __restrict__ topps,
    const int* __restrict__ topks, const float* __restrict__ rps,
    float* __restrict__ out_ids, float* __restrict__ probs) {
  __shared__ unsigned int s_seen[VW];
  __shared__ int s_hist[4096];
  __shared__ unsigned short s_cmax16[NCHUNK];
  __shared__ float s_sval[CAPM];
  __shared__ int s_sidx[CAPM];
  __shared__ float s_e[CAPM];
  __shared__ unsigned char s_keep[CAPM];
  __shared__ float s_wredf[16];
  __shared__ int s_wredi[16];
  __shared__ float s_m, s_denom, s_denom2;
  __shared__ int s_b0, s_cnt, s_p0;

  const int row = blockIdx.x;
  const int tid = threadIdx.x;
  const int lane = tid & 63;
  const int wid = tid >> 6;
  const float rp = rps[row];
  const float irp = 1.0f / rp;
  const float itemp = 1.0f / temps[row];
  const float topp = topps[row];
  const int k = topks[row];
  const size_t base = (size_t)row * V;
  const float4* __restrict__ lg4 = reinterpret_cast<const float4*>(logits + base);
  vfloat4* __restrict__ pr4 = reinterpret_cast<vfloat4*>(probs + base);

  for (int i = tid; i < VW; i += 1024) s_seen[i] = 0u;
  for (int i = tid; i < 4096; i += 1024) s_hist[i] = 0;
  __syncthreads();
  for (int i = tid; i < W; i += 1024) {
    int tok = toks[row * W + i];
    if (tok >= 0 && tok < V) atomicOr(&s_seen[tok >> 5], 1u << (tok & 31));
  }
  __syncthreads();

  float lmax = -INFINITY;
  for (int qb = 0; qb < V4; qb += 1024) {
    const int q = qb + tid;
    unsigned int kmax = 0u;
    if (q < V4) {
      float4 x4 = lg4[q];
      float xs[4] = {x4.x, x4.y, x4.z, x4.w};
      const int j0 = q * 4;
      const int sh = j0 & 31;
      unsigned long long ww = (unsigned long long)s_seen[j0 >> 5] |
                              ((unsigned long long)s_seen[(j0 + 3) >> 5] << 32);
#pragma unroll
      for (int e = 0; e < 4; ++e) {
        float x = xform(xs[e], (ww >> (sh + e)) & 1ull, rp, irp, itemp);
        lmax = fmaxf(lmax, x);
        unsigned int ky = fkey(x);
        kmax = kmax > ky ? kmax : ky;
      }
    }
    unsigned int o;
    o = __shfl_xor(kmax, 1); kmax = kmax > o ? kmax : o;
    o = __shfl_xor(kmax, 2); kmax = kmax > o ? kmax : o;
    if (((lane & 3) == 0) && (q < V4)) s_cmax16[q >> 2] = (unsigned short)(kmax >> 16);
  }
#pragma unroll
  for (int d = 32; d > 0; d >>= 1) lmax = fmaxf(lmax, __shfl_xor(lmax, d));
  if (lane == 0) s_wredf[wid] = lmax;
  __syncthreads();
  for (int i = tid; i < NCHUNK; i += 1024)
    atomicAdd(&s_hist[s_cmax16[i] >> 4], 1);
  __syncthreads();
  if (wid == 1 && lane == 0) {
    float mm = s_wredf[0];
    for (int i = 1; i < 16; ++i) mm = fmaxf(mm, s_wredf[i]);
    s_m = mm;
  }
  if (wid == 0) {
    int sm = 0;
    const int bb = lane * 64;
    for (int i = 0; i < 64; ++i) sm += s_hist[bb + i];
    int sfx = sm;
#pragma unroll
    for (int d = 1; d < 64; d <<= 1) {
      int t = __shfl_down(sfx, d);
      if (lane + d < 64) sfx += t;
    }
    unsigned long long mk = __ballot(sfx >= k);
    const int cstar = 63 - __builtin_clzll(mk);
    const int above = __shfl(sfx, cstar) - __shfl(sm, cstar);
    int h = s_hist[cstar * 64 + lane];
    int sfx2 = h;
#pragma unroll
    for (int d = 1; d < 64; d <<= 1) {
      int t = __shfl_down(sfx2, d);
      if (lane + d < 64) sfx2 += t;
    }
    unsigned long long mk2 = __ballot(above + sfx2 >= k);
    const int boff = 63 - __builtin_clzll(mk2);
    if (lane == 0) { s_b0 = cstar * 64 + boff; s_cnt = 0; }
  }
  __syncthreads();
  const int b0 = s_b0;
  const unsigned int fk0 = ((unsigned int)b0) << 20;
  const int c16 = b0 << 4;
  for (int qb = 0; qb < V4; qb += 1024) {
    const int q = qb + tid;
    const bool act = (q < V4) && ((int)s_cmax16[q >> 2] >= c16);
    float xs[4];
    bool pr[4] = {false, false, false, false};
    const int j0 = q * 4;
    if (act) {
      float4 x4 = lg4[q];
      float raw[4] = {x4.x, x4.y, x4.z, x4.w};
      const int sh = j0 & 31;
      unsigned long long ww = (unsigned long long)s_seen[j0 >> 5] |
                              ((unsigned long long)s_seen[(j0 + 3) >> 5] << 32);
#pragma unroll
      for (int e = 0; e < 4; ++e) {
        xs[e] = xform(raw[e], (ww >> (sh + e)) & 1ull, rp, irp, itemp);
        pr[e] = (fkey(xs[e]) >= fk0);
      }
    }
#pragma unroll
    for (int e = 0; e < 4; ++e) {
      unsigned long long mask = __ballot(pr[e]);
      if (!mask) continue;
      int basep = 0;
      if (lane == 0) basep = atomicAdd(&s_cnt, __popcll(mask));
      basep = __shfl(basep, 0);
      if (pr[e]) {
        int pos = basep + __popcll(mask & ((1ull << lane) - 1ull));
        if (pos < CAPM) { s_sval[pos] = xs[e]; s_sidx[pos] = j0 + e; }
      }
    }
  }
  __syncthreads();
  int G = s_cnt;
  if (G > CAPM) G = CAPM;
  int np2 = 2;
  while (np2 < G) np2 <<= 1;
  for (int i = G + tid; i < np2; i += 1024) {
    s_sval[i] = INFINITY;
    s_sidx[i] = 0x7FFFFFFF;
  }
  __syncthreads();
  for (int size = 2; size <= np2; size <<= 1) {
    for (int stride = size >> 1; stride > 0; stride >>= 1) {
      for (int t2 = tid; t2 < (np2 >> 1); t2 += 1024) {
        int pos = 2 * t2 - (t2 & (stride - 1));
        int qq = pos + stride;
        bool up = ((pos & size) == 0);
        float v1 = s_sval[pos], v2 = s_sval[qq];
        int i1 = s_sidx[pos], i2 = s_sidx[qq];
        bool gt = (v1 > v2) || (v1 == v2 && i1 > i2);
        if (gt == up) {
          s_sval[pos] = v2; s_sval[qq] = v1;
          s_sidx[pos] = i2; s_sidx[qq] = i1;
        }
      }
      __syncthreads();
    }
  }
  const int kk = k > G ? G : k;
  const float kth = s_sval[G - kk];
  const float m = s_m;
  for (int i = tid; i < G; i += 1024) {
    if (s_sval[i] >= kth && (i == 0 || s_sval[i - 1] < kth)) s_p0 = i;
  }
  __syncthreads();
  const int p0 = s_p0;
  float part = 0.0f;
  for (int i = p0 + tid; i < G; i += 1024) {
    float e = expf(s_sval[i] - m);
    s_e[i] = e;
    part += e;
  }
#pragma unroll
  for (int d = 32; d > 0; d >>= 1) part += __shfl_xor(part, d);
  if (lane == 0) s_wredf[wid] = part;
  __syncthreads();
  if (tid == 0) {
    float s = 0.0f;
    for (int i = 0; i < 16; ++i) s += s_wredf[i];
    s_denom = s;
  }
  __syncthreads();
  const float denom = s_denom;
  if (tid == 0) {
    const float cut = 1.0f - topp;
    float cs = 0.0f;
    for (int i = p0; i < G; ++i) {
      cs += s_e[i] / denom;
      s_keep[i] = (cs <= cut) ? 0 : 1;
    }
    s_keep[G - 1] = 1;
  }
  __syncthreads();
  part = 0.0f;
  for (int i = p0 + tid; i < G; i += 1024)
    if (s_keep[i]) part += s_e[i];
#pragma unroll
  for (int d = 32; d > 0; d >>= 1) part += __shfl_xor(part, d);
  if (lane == 0) s_wredf[wid] = part;
  __syncthreads();
  if (tid == 0) {
    float s = 0.0f;
    for (int i = 0; i < 16; ++i) s += s_wredf[i];
    s_denom2 = s;
  }
  __syncthreads();
  const float denom2 = s_denom2;
  for (int i = p0 + tid; i < G; i += 1024)
    s_e[i] = s_keep[i] ? (s_e[i] / denom2) : 0.0f;
  __syncthreads();
  float bs = -INFINITY;
  int bi = 0x7FFFFFFF;
  for (int i = p0 + tid; i < G; i += 1024) {
    if (!s_keep[i]) continue;
    int j = s_sidx[i];
    unsigned int t = (unsigned int)(row * V) + (unsigned int)j;
    unsigned int bb = tf_bits(t);
    float u = __uint_as_float((bb >> 9) | 0x3f800000u) - 1.0f;
    if (u < TINYF) u = TINYF;
    float g = -logf(-logf(u));
    float sc = s_sval[i] + g;
    if (sc > bs || (sc == bs && j < bi)) { bs = sc; bi = j; }
  }
  const unsigned int kkey = fkey(kth);
  const int k16 = (int)(kkey >> 16);
  for (int q = tid; q < V4; q += 1024) {
    vfloat4 o = (vfloat4){0.0f, 0.0f, 0.0f, 0.0f};
    if ((int)s_cmax16[q >> 2] >= k16) {
      float4 x4 = lg4[q];
      float raw[4] = {x4.x, x4.y, x4.z, x4.w};
      float os[4];
      const int j0 = q * 4;
      const int sh = j0 & 31;
      unsigned long long ww = (unsigned long long)s_seen[j0 >> 5] |
                              ((unsigned long long)s_seen[(j0 + 3) >> 5] << 32);
#pragma unroll
      for (int e = 0; e < 4; ++e) {
        float x = xform(raw[e], (ww >> (sh + e)) & 1ull, rp, irp, itemp);
        float pr = 0.0f;
        if (x >= kth) {
          int j = j0 + e;
          int lo = p0, hi = G;
          while (lo < hi) {
            int mid = (lo + hi) >> 1;
            float v = s_sval[mid];
            int id = s_sidx[mid];
            if (v < x || (v == x && id < j)) lo = mid + 1; else hi = mid;
          }
          pr = s_e[lo];
        }
        os[e] = pr;
      }
      o.x = os[0]; o.y = os[1]; o.z = os[2]; o.w = os[3];
    }
    __builtin_nontemporal_store(o, &pr4[q]);
  }
#pragma unroll
  for (int d = 32; d > 0; d >>= 1) {
    float ov = __shfl_down(bs, d);
    int oi = __shfl_down(bi, d);
    if (ov > bs || (ov == bs && oi < bi)) { bs = ov; bi = oi; }
  }
  if (lane == 0) { s_wredf[wid] = bs; s_wredi[wid] = bi; }
  __syncthreads();
  if (tid == 0) {
    float bb = s_wredf[0];
    int bj = s_wredi[0];
    for (int i = 1; i < 16; ++i) {
      if (s_wredf[i] > bb || (s_wredf[i] == bb && s_wredi[i] < bj)) {
        bb = s_wredf[i];
        bj = s_wredi[i];
      }
    }
    out_ids[row] = (float)bj;
  }
}

extern "C" void kernel_launch(void* const* d_in, const int* in_sizes, int n_in,
                              void* d_out, int out_size, void* d_ws, size_t ws_size,
                              hipStream_t stream) {
  (void)in_sizes; (void)out_size;
  if (n_in < 6) return;
  const float* logits = (const float*)d_in[0];
  const int* toks = (const int*)d_in[1];
  const float* temps = (const float*)d_in[2];
  const float* topps = (const float*)d_in[3];
  const int* topks = (const int*)d_in[4];
  const float* rps = (const float*)d_in[5];
  float* out = (float*)d_out;            // [0,256): ids as float; [256,...): probs
  float* probs = out + NROWS;

  if (ws_size >= WS_NEED && d_ws != nullptr) {
    char* w = (char*)d_ws;
    unsigned short* ws_cmax = (unsigned short*)(w + WS_CMAX);
    float* ws_bmax = (float*)(w + WS_BMAX);
    float* ws_kth = (float*)(w + WS_KTH);
    int* ws_G = (int*)(w + WS_G);
    int* ws_p0 = (int*)(w + WS_P0);
    float* ws_sval = (float*)(w + WS_SVAL);
    int* ws_sidx = (int*)(w + WS_SIDX);
    float* ws_pe = (float*)(w + WS_PE);
    kA_chunkmax<<<dim3(NROWS * NSLICE), dim3(256), 0, stream>>>(
        logits, toks, temps, rps, ws_cmax, ws_bmax);
    kB_select<<<dim3(NROWS), dim3(1024), 0, stream>>>(
        logits, toks, temps, topps, topks, rps, ws_cmax, ws_bmax,
        ws_kth, ws_G, ws_p0, ws_sval, ws_sidx, ws_pe, out);
    kC_probs<<<dim3(NROWS * NSLICE), dim3(256), 0, stream>>>(
        logits, toks, temps, rps, ws_cmax, ws_kth, ws_G, ws_p0,
        ws_sval, ws_sidx, ws_pe, probs);
  } else {
    sampler_mono<<<dim3(NROWS), dim3(1024), 0, stream>>>(
        logits, toks, temps, topps, topks, rps, out, probs);
  }
}

// Round 7
// 159.842 us; speedup vs baseline: 1.5599x; 1.5599x over previous
//
#include <hip/hip_runtime.h>

#define V 128000
#define V4 (V / 4)
#define NCHUNK (V / 16)      // 8000 chunk-max entries (16 elems each)
#define NROWS 256
#define NSLICE 8
#define SL4 (V4 / NSLICE)    // 4000 float4 per slice
#define W 200
#define VW (V / 32)          // 4000 words of seen-bitmask
#define CAP 4096             // survivor capacity
#define CAPM 8192            // mono-kernel capacity
#define TINYF 1.17549435e-38f

// ---- d_ws layout ----
#define WS_CMAX   0u          // u16[256][8000]
#define WS_BMAX   4104192u    // float[256][8]
#define WS_NEED   16777216u

typedef float vfloat4 __attribute__((ext_vector_type(4)));

__device__ __forceinline__ unsigned int fkey(float x) {
  unsigned int u = __float_as_uint(x);
  return (u & 0x80000000u) ? ~u : (u | 0x80000000u);
}
__device__ __forceinline__ float ikey(unsigned int k) {
  unsigned int u = (k & 0x80000000u) ? (k & 0x7FFFFFFFu) : ~k;
  return __uint_as_float(u);
}

// ---- jax threefry2x32, partitionable: counter=(0,t), key=(0,42), fold=xor ----
__device__ __forceinline__ unsigned int tf_bits(unsigned int t) {
  const unsigned int k0 = 0u, k1 = 42u;
  const unsigned int ks2 = k0 ^ k1 ^ 0x1BD11BDAu;
  unsigned int x0 = 0u + k0, x1 = t + k1;
  const unsigned int ksArr[3] = {k0, k1, ks2};
  const int RA[4] = {13, 15, 26, 6};
  const int RB[4] = {17, 29, 16, 24};
#pragma unroll
  for (int i = 0; i < 5; ++i) {
#pragma unroll
    for (int j = 0; j < 4; ++j) {
      int r = (i & 1) ? RB[j] : RA[j];
      x0 += x1;
      x1 = (x1 << r) | (x1 >> (32 - r));
      x1 ^= x0;
    }
    x0 += ksArr[(i + 1) % 3];
    x1 += ksArr[(i + 2) % 3] + (unsigned int)(i + 1);
  }
  return x0 ^ x1;
}

__device__ __forceinline__ float xform(float x, bool seen, float rp, float irp,
                                        float itemp) {
  if (seen) x = (x > 0.0f) ? x * irp : x * rp;
  return x * itemp;
}

// ====== Kernel AZ: transform + chunk-max + slice-max + zero-fill probs ======
__global__ __launch_bounds__(256) void kAZ_chunkmax(
    const float* __restrict__ logits, const int* __restrict__ toks,
    const float* __restrict__ temps, const float* __restrict__ rps,
    unsigned short* __restrict__ ws_cmax, float* __restrict__ ws_bmax,
    float* __restrict__ probs) {
  __shared__ unsigned int s_seen[VW];
  __shared__ float s_red[4];
  const int row = blockIdx.x >> 3;
  const int slice = blockIdx.x & 7;
  const int tid = threadIdx.x;
  const int lane = tid & 63;
  const int wid = tid >> 6;
  const float rp = rps[row];
  const float irp = 1.0f / rp;
  const float itemp = 1.0f / temps[row];
  const size_t base = (size_t)row * V;
  const float4* __restrict__ lg4 = reinterpret_cast<const float4*>(logits + base);
  vfloat4* __restrict__ pr4 = reinterpret_cast<vfloat4*>(probs + base);

  for (int i = tid; i < VW; i += 256) s_seen[i] = 0u;
  __syncthreads();
  for (int i = tid; i < W; i += 256) {
    int tok = toks[row * W + i];
    if (tok >= 0 && tok < V) atomicOr(&s_seen[tok >> 5], 1u << (tok & 31));
  }
  __syncthreads();

  float lmax = -INFINITY;
  const int q0 = slice * SL4;
  const vfloat4 z4 = (vfloat4){0.0f, 0.0f, 0.0f, 0.0f};
  for (int qi = tid; qi < SL4; qi += 256) {
    const int q = q0 + qi;
    float4 x4 = lg4[q];
    pr4[q] = z4;                       // zero-fill probs (plain cached store)
    float xs[4] = {x4.x, x4.y, x4.z, x4.w};
    const int j0 = q * 4;
    const int sh = j0 & 31;
    unsigned long long ww = (unsigned long long)s_seen[j0 >> 5] |
                            ((unsigned long long)s_seen[(j0 + 3) >> 5] << 32);
    unsigned int kmax = 0u;
#pragma unroll
    for (int e = 0; e < 4; ++e) {
      float x = xform(xs[e], (ww >> (sh + e)) & 1ull, rp, irp, itemp);
      lmax = fmaxf(lmax, x);
      unsigned int ky = fkey(x);
      kmax = kmax > ky ? kmax : ky;
    }
    unsigned int o;
    o = __shfl_xor(kmax, 1); kmax = kmax > o ? kmax : o;
    o = __shfl_xor(kmax, 2); kmax = kmax > o ? kmax : o;
    if ((lane & 3) == 0) ws_cmax[row * NCHUNK + (q >> 2)] = (unsigned short)(kmax >> 16);
  }
#pragma unroll
  for (int d = 32; d > 0; d >>= 1) lmax = fmaxf(lmax, __shfl_xor(lmax, d));
  if (lane == 0) s_red[wid] = lmax;
  __syncthreads();
  if (tid == 0) {
    float mm = fmaxf(fmaxf(s_red[0], s_red[1]), fmaxf(s_red[2], s_red[3]));
    ws_bmax[row * NSLICE + slice] = mm;
  }
}

// ====== Kernel B: select + gather + u64 sort + top-p + sample + scatter ======
__global__ __launch_bounds__(1024, 8) void kB_select(
    const float* __restrict__ logits, const int* __restrict__ toks,
    const float* __restrict__ temps, const float* __restrict__ topps,
    const int* __restrict__ topks, const float* __restrict__ rps,
    const unsigned short* __restrict__ ws_cmax, const float* __restrict__ ws_bmax,
    float* __restrict__ out_ids, float* __restrict__ probs) {
  __shared__ unsigned long long s_key[CAP];       // 32 KB; [0:2048) hosts hist early
  __shared__ unsigned int s_seen_e[4096];         // 16 KB; seen-mask, then s_e
  __shared__ unsigned short s_cmax_keep[8192];    // 16 KB; cmax16, then keep
  __shared__ float s_wredf[16];
  __shared__ int s_wredi[16];
  __shared__ float s_mv, s_dn1, s_dn2;
  __shared__ int s_b0, s_cnt, s_p0v;

  int* s_hist = (int*)s_key;                      // alias (dead before keys written)
  unsigned int* s_seen = s_seen_e;                // alias (dead after gather)
  float* s_e = (float*)s_seen_e;
  unsigned short* s_cmax16 = s_cmax_keep;         // alias (dead after gather)
  unsigned char* s_keep = (unsigned char*)s_cmax_keep;

  const int row = blockIdx.x;
  const int tid = threadIdx.x;
  const int lane = tid & 63;
  const int wid = tid >> 6;
  const float rp = rps[row];
  const float irp = 1.0f / rp;
  const float itemp = 1.0f / temps[row];
  const float topp = topps[row];
  const int k = topks[row];
  const size_t base = (size_t)row * V;
  const float4* __restrict__ lg4 = reinterpret_cast<const float4*>(logits + base);
  float* __restrict__ prow = probs + base;

  // init: seen=0, hist=0, cmax->LDS
  for (int i = tid; i < VW; i += 1024) s_seen[i] = 0u;
  for (int i = tid; i < 4096; i += 1024) s_hist[i] = 0;
  {
    const unsigned int* cm32 = reinterpret_cast<const unsigned int*>(ws_cmax + row * NCHUNK);
    unsigned int* sc32 = reinterpret_cast<unsigned int*>(s_cmax16);
    for (int i = tid; i < NCHUNK / 2; i += 1024) sc32[i] = cm32[i];
  }
  __syncthreads();
  for (int i = tid; i < W; i += 1024) {
    int tok = toks[row * W + i];
    if (tok >= 0 && tok < V) atomicOr(&s_seen[tok >> 5], 1u << (tok & 31));
  }
  __syncthreads();

  // chunk-max histogram
  for (int i = tid; i < NCHUNK; i += 1024)
    atomicAdd(&s_hist[s_cmax16[i] >> 4], 1);
  __syncthreads();

  // bucket select (wave 0); row max (wave 1)
  if (wid == 1 && lane == 0) {
    float mm = ws_bmax[row * NSLICE];
    for (int i = 1; i < NSLICE; ++i) mm = fmaxf(mm, ws_bmax[row * NSLICE + i]);
    s_mv = mm;
  }
  if (wid == 0) {
    int sm = 0;
    const int bb = lane * 64;
    for (int i = 0; i < 64; ++i) sm += s_hist[bb + i];
    int sfx = sm;
#pragma unroll
    for (int d = 1; d < 64; d <<= 1) {
      int t = __shfl_down(sfx, d);
      if (lane + d < 64) sfx += t;
    }
    unsigned long long mk = __ballot(sfx >= k);
    const int cstar = 63 - __builtin_clzll(mk);
    const int above = __shfl(sfx, cstar) - __shfl(sm, cstar);
    int h = s_hist[cstar * 64 + lane];
    int sfx2 = h;
#pragma unroll
    for (int d = 1; d < 64; d <<= 1) {
      int t = __shfl_down(sfx2, d);
      if (lane + d < 64) sfx2 += t;
    }
    unsigned long long mk2 = __ballot(above + sfx2 >= k);
    const int boff = 63 - __builtin_clzll(mk2);
    if (lane == 0) { s_b0 = cstar * 64 + boff; s_cnt = 0; }
  }
  __syncthreads();
  const int b0 = s_b0;

  // gather candidates as u64 keys (fkey<<32 | idx)
  const unsigned int fk0 = ((unsigned int)b0) << 20;
  const int c16 = b0 << 4;
  for (int qb = 0; qb < V4; qb += 1024) {
    const int q = qb + tid;
    const bool act = (q < V4) && ((int)s_cmax16[q >> 2] >= c16);
    unsigned int ks[4];
    bool pr[4] = {false, false, false, false};
    const int j0 = q * 4;
    if (act) {
      float4 x4 = lg4[q];
      float raw[4] = {x4.x, x4.y, x4.z, x4.w};
      const int sh = j0 & 31;
      unsigned long long ww = (unsigned long long)s_seen[j0 >> 5] |
                              ((unsigned long long)s_seen[(j0 + 3) >> 5] << 32);
#pragma unroll
      for (int e = 0; e < 4; ++e) {
        float x = xform(raw[e], (ww >> (sh + e)) & 1ull, rp, irp, itemp);
        ks[e] = fkey(x);
        pr[e] = (ks[e] >= fk0);
      }
    }
#pragma unroll
    for (int e = 0; e < 4; ++e) {
      unsigned long long mask = __ballot(pr[e]);
      if (!mask) continue;
      int basep = 0;
      if (lane == 0) basep = atomicAdd(&s_cnt, __popcll(mask));
      basep = __shfl(basep, 0);
      if (pr[e]) {
        int pos = basep + __popcll(mask & ((1ull << lane) - 1ull));
        if (pos < CAP)
          s_key[pos] = ((unsigned long long)ks[e] << 32) | (unsigned int)(j0 + e);
      }
    }
  }
  __syncthreads();
  int G = s_cnt;
  if (G > CAP) G = CAP;

  // bitonic sort u64 ascending (== (value, index) ascending)
  int np2 = 2;
  while (np2 < G) np2 <<= 1;
  for (int i = G + tid; i < np2; i += 1024) s_key[i] = ~0ull;
  __syncthreads();
  for (int size = 2; size <= np2; size <<= 1) {
    for (int stride = size >> 1; stride > 0; stride >>= 1) {
      for (int t2 = tid; t2 < (np2 >> 1); t2 += 1024) {
        int pos = 2 * t2 - (t2 & (stride - 1));
        int qq = pos + stride;
        bool up = ((pos & size) == 0);
        unsigned long long a = s_key[pos], b = s_key[qq];
        if ((a > b) == up) { s_key[pos] = b; s_key[qq] = a; }
      }
      __syncthreads();
    }
  }

  // exact kth + survivor range [p0, G)
  const int kk = k > G ? G : k;
  const unsigned int khi = (unsigned int)(s_key[G - kk] >> 32);
  const float kth = ikey(khi);
  const float m = s_mv;
  for (int i = tid; i < G; i += 1024) {
    unsigned int hi = (unsigned int)(s_key[i] >> 32);
    if (hi >= khi && (i == 0 || (unsigned int)(s_key[i - 1] >> 32) < khi)) s_p0v = i;
  }
  __syncthreads();
  const int p0 = s_p0v;
  (void)kth;

  // softmax denom over survivors
  float part = 0.0f;
  for (int i = p0 + tid; i < G; i += 1024) {
    float x = ikey((unsigned int)(s_key[i] >> 32));
    float e = expf(x - m);
    s_e[i] = e;
    part += e;
  }
#pragma unroll
  for (int d = 32; d > 0; d >>= 1) part += __shfl_xor(part, d);
  if (lane == 0) s_wredf[wid] = part;
  __syncthreads();
  if (tid == 0) {
    float s = 0.0f;
    for (int i = 0; i < 16; ++i) s += s_wredf[i];
    s_dn1 = s;
  }
  __syncthreads();
  const float denom = s_dn1;

  // sequential cumsum + top-p mask (batched, last kept)
  if (tid == 0) {
    const float cut = 1.0f - topp;
    float cs = 0.0f;
    int i = p0;
    for (; i + 8 <= G; i += 8) {
      float v0 = s_e[i], v1 = s_e[i + 1], v2 = s_e[i + 2], v3 = s_e[i + 3];
      float v4 = s_e[i + 4], v5 = s_e[i + 5], v6 = s_e[i + 6], v7 = s_e[i + 7];
      float d0 = v0 / denom, d1 = v1 / denom, d2 = v2 / denom, d3 = v3 / denom;
      float d4 = v4 / denom, d5 = v5 / denom, d6 = v6 / denom, d7 = v7 / denom;
      cs += d0; s_keep[i] = (cs <= cut) ? 0 : 1;
      cs += d1; s_keep[i + 1] = (cs <= cut) ? 0 : 1;
      cs += d2; s_keep[i + 2] = (cs <= cut) ? 0 : 1;
      cs += d3; s_keep[i + 3] = (cs <= cut) ? 0 : 1;
      cs += d4; s_keep[i + 4] = (cs <= cut) ? 0 : 1;
      cs += d5; s_keep[i + 5] = (cs <= cut) ? 0 : 1;
      cs += d6; s_keep[i + 6] = (cs <= cut) ? 0 : 1;
      cs += d7; s_keep[i + 7] = (cs <= cut) ? 0 : 1;
    }
    for (; i < G; ++i) {
      cs += s_e[i] / denom;
      s_keep[i] = (cs <= cut) ? 0 : 1;
    }
    s_keep[G - 1] = 1;
  }
  __syncthreads();

  // final denom over kept
  part = 0.0f;
  for (int i = p0 + tid; i < G; i += 1024)
    if (s_keep[i]) part += s_e[i];
#pragma unroll
  for (int d = 32; d > 0; d >>= 1) part += __shfl_xor(part, d);
  if (lane == 0) s_wredf[wid] = part;
  __syncthreads();
  if (tid == 0) {
    float s = 0.0f;
    for (int i = 0; i < 16; ++i) s += s_wredf[i];
    s_dn2 = s;
  }
  __syncthreads();
  const float denom2 = s_dn2;

  for (int i = p0 + tid; i < G; i += 1024)
    s_e[i] = s_keep[i] ? (s_e[i] / denom2) : 0.0f;
  __syncthreads();

  // Gumbel argmax over kept survivors
  float bs = -INFINITY;
  int bi = 0x7FFFFFFF;
  for (int i = p0 + tid; i < G; i += 1024) {
    if (!s_keep[i]) continue;
    unsigned long long kv = s_key[i];
    int j = (int)(kv & 0xFFFFFFFFull);
    float x = ikey((unsigned int)(kv >> 32));
    unsigned int t = (unsigned int)(row * V) + (unsigned int)j;
    unsigned int bb = tf_bits(t);
    float u = __uint_as_float((bb >> 9) | 0x3f800000u) - 1.0f;
    if (u < TINYF) u = TINYF;
    float g = -logf(-logf(u));
    float sc = x + g;
    if (sc > bs || (sc == bs && j < bi)) { bs = sc; bi = j; }
  }

  // scatter nonzero probs (zeros already laid down by kAZ)
  for (int i = p0 + tid; i < G; i += 1024) {
    int j = (int)(s_key[i] & 0xFFFFFFFFull);
    prow[j] = s_e[i];
  }

  // argmax reduce -> sampled id
#pragma unroll
  for (int d = 32; d > 0; d >>= 1) {
    float ov = __shfl_down(bs, d);
    int oi = __shfl_down(bi, d);
    if (ov > bs || (ov == bs && oi < bi)) { bs = ov; bi = oi; }
  }
  if (lane == 0) { s_wredf[wid] = bs; s_wredi[wid] = bi; }
  __syncthreads();
  if (tid == 0) {
    float bb = s_wredf[0];
    int bj = s_wredi[0];
    for (int i = 1; i < 16; ++i) {
      if (s_wredf[i] > bb || (s_wredf[i] == bb && s_wredi[i] < bj)) {
        bb = s_wredf[i];
        bj = s_wredi[i];
      }
    }
    out_ids[row] = (float)bj;
  }
}

// ================== Fallback: monolithic kernel (ws too small) ==================
__global__ __launch_bounds__(1024, 1) void sampler_mono(
    const float* __restrict__ logits, const int* __restrict__ toks,
    const float* __restrict__ temps, const float* __restrict__ topps,
    const int* __restrict__ topks, const float* __restrict__ rps,
    float* __restrict__ out_ids, float* __restrict__ probs) {
  __shared__ unsigned int s_seen[VW];
  __shared__ int s_hist[4096];
  __shared__ unsigned short s_cmax16[NCHUNK];
  __shared__ float s_sval[CAPM];
  __shared__ int s_sidx[CAPM];
  __shared__ float s_e[CAPM];
  __shared__ unsigned char s_keep[CAPM];
  __shared__ float s_wredf[16];
  __shared__ int s_wredi[16];
  __shared__ float s_m, s_denom, s_denom2;
  __shared__ int s_b0, s_cnt, s_p0;

  const int row = blockIdx.x;
  const int tid = threadIdx.x;
  const int lane = tid & 63;
  const int wid = tid >> 6;
  const float rp = rps[row];
  const float irp = 1.0f / rp;
  const float itemp = 1.0f / temps[row];
  const float topp = topps[row];
  const int k = topks[row];
  const size_t base = (size_t)row * V;
  const float4* __restrict__ lg4 = reinterpret_cast<const float4*>(logits + base);
  vfloat4* __restrict__ pr4 = reinterpret_cast<vfloat4*>(probs + base);

  for (int i = tid; i < VW; i += 1024) s_seen[i] = 0u;
  for (int i = tid; i < 4096; i += 1024) s_hist[i] = 0;
  __syncthreads();
  for (int i = tid; i < W; i += 1024) {
    int tok = toks[row * W + i];
    if (tok >= 0 && tok < V) atomicOr(&s_seen[tok >> 5], 1u << (tok & 31));
  }
  __syncthreads();

  float lmax = -INFINITY;
  for (int qb = 0; qb < V4; qb += 1024) {
    const int q = qb + tid;
    unsigned int kmax = 0u;
    if (q < V4) {
      float4 x4 = lg4[q];
      float xs[4] = {x4.x, x4.y, x4.z, x4.w};
      const int j0 = q * 4;
      const int sh = j0 & 31;
      unsigned long long ww = (unsigned long long)s_seen[j0 >> 5] |
                              ((unsigned long long)s_seen[(j0 + 3) >> 5] << 32);
#pragma unroll
      for (int e = 0; e < 4; ++e) {
        float x = xform(xs[e], (ww >> (sh + e)) & 1ull, rp, irp, itemp);
        lmax = fmaxf(lmax, x);
        unsigned int ky = fkey(x);
        kmax = kmax > ky ? kmax : ky;
      }
    }
    unsigned int o;
    o = __shfl_xor(kmax, 1); kmax = kmax > o ? kmax : o;
    o = __shfl_xor(kmax, 2); kmax = kmax > o ? kmax : o;
    if (((lane & 3) == 0) && (q < V4)) s_cmax16[q >> 2] = (unsigned short)(kmax >> 16);
  }
#pragma unroll
  for (int d = 32; d > 0; d >>= 1) lmax = fmaxf(lmax, __shfl_xor(lmax, d));
  if (lane == 0) s_wredf[wid] = lmax;
  __syncthreads();
  for (int i = tid; i < NCHUNK; i += 1024)
    atomicAdd(&s_hist[s_cmax16[i] >> 4], 1);
  __syncthreads();
  if (wid == 1 && lane == 0) {
    float mm = s_wredf[0];
    for (int i = 1; i < 16; ++i) mm = fmaxf(mm, s_wredf[i]);
    s_m = mm;
  }
  if (wid == 0) {
    int sm = 0;
    const int bb = lane * 64;
    for (int i = 0; i < 64; ++i) sm += s_hist[bb + i];
    int sfx = sm;
#pragma unroll
    for (int d = 1; d < 64; d <<= 1) {
      int t = __shfl_down(sfx, d);
      if (lane + d < 64) sfx += t;
    }
    unsigned long long mk = __ballot(sfx >= k);
    const int cstar = 63 - __builtin_clzll(mk);
    const int above = __shfl(sfx, cstar) - __shfl(sm, cstar);
    int h = s_hist[cstar * 64 + lane];
    int sfx2 = h;
#pragma unroll
    for (int d = 1; d < 64; d <<= 1) {
      int t = __shfl_down(sfx2, d);
      if (lane + d < 64) sfx2 += t;
    }
    unsigned long long mk2 = __ballot(above + sfx2 >= k);
    const int boff = 63 - __builtin_clzll(mk2);
    if (lane == 0) { s_b0 = cstar * 64 + boff; s_cnt = 0; }
  }
  __syncthreads();
  const int b0 = s_b0;
  const unsigned int fk0 = ((unsigned int)b0) << 20;
  const int c16 = b0 << 4;
  for (int qb = 0; qb < V4; qb += 1024) {
    const int q = qb + tid;
    const bool act = (q < V4) && ((int)s_cmax16[q >> 2] >= c16);
    float xs[4];
    bool pr[4] = {false, false, false, false};
    const int j0 = q * 4;
    if (act) {
      float4 x4 = lg4[q];
      float raw[4] = {x4.x, x4.y, x4.z, x4.w};
      const int sh = j0 & 31;
      unsigned long long ww = (unsigned long long)s_seen[j0 >> 5] |
                              ((unsigned long long)s_seen[(j0 + 3) >> 5] << 32);
#pragma unroll
      for (int e = 0; e < 4; ++e) {
        xs[e] = xform(raw[e], (ww >> (sh + e)) & 1ull, rp, irp, itemp);
        pr[e] = (fkey(xs[e]) >= fk0);
      }
    }
#pragma unroll
    for (int e = 0; e < 4; ++e) {
      unsigned long long mask = __ballot(pr[e]);
      if (!mask) continue;
      int basep = 0;
      if (lane == 0) basep = atomicAdd(&s_cnt, __popcll(mask));
      basep = __shfl(basep, 0);
      if (pr[e]) {
        int pos = basep + __popcll(mask & ((1ull << lane) - 1ull));
        if (pos < CAPM) { s_sval[pos] = xs[e]; s_sidx[pos] = j0 + e; }
      }
    }
  }
  __syncthreads();
  int G = s_cnt;
  if (G > CAPM) G = CAPM;
  int np2 = 2;
  while (np2 < G) np2 <<= 1;
  for (int i = G + tid; i < np2; i += 1024) {
    s_sval[i] = INFINITY;
    s_sidx[i] = 0x7FFFFFFF;
  }
  __syncthreads();
  for (int size = 2; size <= np2; size <<= 1) {
    for (int stride = size >> 1; stride > 0; stride >>= 1) {
      for (int t2 = tid; t2 < (np2 >> 1); t2 += 1024) {
        int pos = 2 * t2 - (t2 & (stride - 1));
        int qq = pos + stride;
        bool up = ((pos & size) == 0);
        float v1 = s_sval[pos], v2 = s_sval[qq];
        int i1 = s_sidx[pos], i2 = s_sidx[qq];
        bool gt = (v1 > v2) || (v1 == v2 && i1 > i2);
        if (gt == up) {
          s_sval[pos] = v2; s_sval[qq] = v1;
          s_sidx[pos] = i2; s_sidx[qq] = i1;
        }
      }
      __syncthreads();
    }
  }
  const int kk = k > G ? G : k;
  const float kth = s_sval[G - kk];
  const float m = s_m;
  for (int i = tid; i < G; i += 1024) {
    if (s_sval[i] >= kth && (i == 0 || s_sval[i - 1] < kth)) s_p0 = i;
  }
  __syncthreads();
  const int p0 = s_p0;
  float part = 0.0f;
  for (int i = p0 + tid; i < G; i += 1024) {
    float e = expf(s_sval[i] - m);
    s_e[i] = e;
    part += e;
  }
#pragma unroll
  for (int d = 32; d > 0; d >>= 1) part += __shfl_xor(part, d);
  if (lane == 0) s_wredf[wid] = part;
  __syncthreads();
  if (tid == 0) {
    float s = 0.0f;
    for (int i = 0; i < 16; ++i) s += s_wredf[i];
    s_denom = s;
  }
  __syncthreads();
  const float denom = s_denom;
  if (tid == 0) {
    const float cut = 1.0f - topp;
    float cs = 0.0f;
    for (int i = p0; i < G; ++i) {
      cs += s_e[i] / denom;
      s_keep[i] = (cs <= cut) ? 0 : 1;
    }
    s_keep[G - 1] = 1;
  }
  __syncthreads();
  part = 0.0f;
  for (int i = p0 + tid; i < G; i += 1024)
    if (s_keep[i]) part += s_e[i];
#pragma unroll
  for (int d = 32; d > 0; d >>= 1) part += __shfl_xor(part, d);
  if (lane == 0) s_wredf[wid] = part;
  __syncthreads();
  if (tid == 0) {
    float s = 0.0f;
    for (int i = 0; i < 16; ++i) s += s_wredf[i];
    s_denom2 = s;
  }
  __syncthreads();
  const float denom2 = s_denom2;
  for (int i = p0 + tid; i < G; i += 1024)
    s_e[i] = s_keep[i] ? (s_e[i] / denom2) : 0.0f;
  __syncthreads();
  float bs = -INFINITY;
  int bi = 0x7FFFFFFF;
  for (int i = p0 + tid; i < G; i += 1024) {
    if (!s_keep[i]) continue;
    int j = s_sidx[i];
    unsigned int t = (unsigned int)(row * V) + (unsigned int)j;
    unsigned int bb = tf_bits(t);
    float u = __uint_as_float((bb >> 9) | 0x3f800000u) - 1.0f;
    if (u < TINYF) u = TINYF;
    float g = -logf(-logf(u));
    float sc = s_sval[i] + g;
    if (sc > bs || (sc == bs && j < bi)) { bs = sc; bi = j; }
  }
  const unsigned int kkey = fkey(kth);
  const int k16 = (int)(kkey >> 16);
  for (int q = tid; q < V4; q += 1024) {
    vfloat4 o = (vfloat4){0.0f, 0.0f, 0.0f, 0.0f};
    if ((int)s_cmax16[q >> 2] >= k16) {
      float4 x4 = lg4[q];
      float raw[4] = {x4.x, x4.y, x4.z, x4.w};
      float os[4];
      const int j0 = q * 4;
      const int sh = j0 & 31;
      unsigned long long ww = (unsigned long long)s_seen[j0 >> 5] |
                              ((unsigned long long)s_seen[(j0 + 3) >> 5] << 32);
#pragma unroll
      for (int e = 0; e < 4; ++e) {
        float x = xform(raw[e], (ww >> (sh + e)) & 1ull, rp, irp, itemp);
        float pr = 0.0f;
        if (x >= kth) {
          int j = j0 + e;
          int lo = p0, hi = G;
          while (lo < hi) {
            int mid = (lo + hi) >> 1;
            float v = s_sval[mid];
            int id = s_sidx[mid];
            if (v < x || (v == x && id < j)) lo = mid + 1; else hi = mid;
          }
          pr = s_e[lo];
        }
        os[e] = pr;
      }
      o.x = os[0]; o.y = os[1]; o.z = os[2]; o.w = os[3];
    }
    pr4[q] = o;
  }
#pragma unroll
  for (int d = 32; d > 0; d >>= 1) {
    float ov = __shfl_down(bs, d);
    int oi = __shfl_down(bi, d);
    if (ov > bs || (ov == bs && oi < bi)) { bs = ov; bi = oi; }
  }
  if (lane == 0) { s_wredf[wid] = bs; s_wredi[wid] = bi; }
  __syncthreads();
  if (tid == 0) {
    float bb = s_wredf[0];
    int bj = s_wredi[0];
    for (int i = 1; i < 16; ++i) {
      if (s_wredf[i] > bb || (s_wredf[i] == bb && s_wredi[i] < bj)) {
        bb = s_wredf[i];
        bj = s_wredi[i];
      }
    }
    out_ids[row] = (float)bj;
  }
}

extern "C" void kernel_launch(void* const* d_in, const int* in_sizes, int n_in,
                              void* d_out, int out_size, void* d_ws, size_t ws_size,
                              hipStream_t stream) {
  (void)in_sizes; (void)out_size;
  if (n_in < 6) return;
  const float* logits = (const float*)d_in[0];
  const int* toks = (const int*)d_in[1];
  const float* temps = (const float*)d_in[2];
  const float* topps = (const float*)d_in[3];
  const int* topks = (const int*)d_in[4];
  const float* rps = (const float*)d_in[5];
  float* out = (float*)d_out;            // [0,256): ids as float; [256,...): probs
  float* probs = out + NROWS;

  if (ws_size >= WS_NEED && d_ws != nullptr) {
    char* w = (char*)d_ws;
    unsigned short* ws_cmax = (unsigned short*)(w + WS_CMAX);
    float* ws_bmax = (float*)(w + WS_BMAX);
    kAZ_chunkmax<<<dim3(NROWS * NSLICE), dim3(256), 0, stream>>>(
        logits, toks, temps, rps, ws_cmax, ws_bmax, probs);
    kB_select<<<dim3(NROWS), dim3(1024), 0, stream>>>(
        logits, toks, temps, topps, topks, rps, ws_cmax, ws_bmax, out, probs);
  } else {
    sampler_mono<<<dim3(NROWS), dim3(1024), 0, stream>>>(
        logits, toks, temps, topps, topks, rps, out, probs);
  }
}

// Round 8
// 131.387 us; speedup vs baseline: 1.8978x; 1.2166x over previous
//
#include <hip/hip_runtime.h>

#define V 128000
#define V4 (V / 4)
#define NCHUNK (V / 16)      // 8000 chunk-max entries (16 elems each)
#define NROWS 256
#define NSLICE 8
#define SL4 (V4 / NSLICE)    // 4000 float4 per slice
#define W 200
#define VW (V / 32)          // 4000 words of seen-bitmask
#define CAP 4096             // candidate capacity
#define CAPS 2048            // survivor capacity (k<=1024 + ties)
#define CAPM 8192            // mono-kernel capacity
#define TINYF 1.17549435e-38f

// ---- d_ws layout ----
#define WS_CMAX   0u          // u16[256][8000]
#define WS_BMAX   4104192u    // float[256][8]
#define WS_NEED   16777216u

typedef float vfloat4 __attribute__((ext_vector_type(4)));

__device__ __forceinline__ unsigned int fkey(float x) {
  unsigned int u = __float_as_uint(x);
  return (u & 0x80000000u) ? ~u : (u | 0x80000000u);
}
__device__ __forceinline__ float ikey(unsigned int k) {
  unsigned int u = (k & 0x80000000u) ? (k & 0x7FFFFFFFu) : ~k;
  return __uint_as_float(u);
}

// ---- jax threefry2x32, partitionable: counter=(0,t), key=(0,42), fold=xor ----
__device__ __forceinline__ unsigned int tf_bits(unsigned int t) {
  const unsigned int k0 = 0u, k1 = 42u;
  const unsigned int ks2 = k0 ^ k1 ^ 0x1BD11BDAu;
  unsigned int x0 = 0u + k0, x1 = t + k1;
  const unsigned int ksArr[3] = {k0, k1, ks2};
  const int RA[4] = {13, 15, 26, 6};
  const int RB[4] = {17, 29, 16, 24};
#pragma unroll
  for (int i = 0; i < 5; ++i) {
#pragma unroll
    for (int j = 0; j < 4; ++j) {
      int r = (i & 1) ? RB[j] : RA[j];
      x0 += x1;
      x1 = (x1 << r) | (x1 >> (32 - r));
      x1 ^= x0;
    }
    x0 += ksArr[(i + 1) % 3];
    x1 += ksArr[(i + 2) % 3] + (unsigned int)(i + 1);
  }
  return x0 ^ x1;
}

__device__ __forceinline__ float xform(float x, bool seen, float rp, float irp,
                                        float itemp) {
  if (seen) x = (x > 0.0f) ? x * irp : x * rp;
  return x * itemp;
}

// Wave-parallel suffix select over a 4096-bucket histogram (wave 0 only).
// Finds highest bucket b with (count in buckets >= b) >= need.
// out_b = b, out_rem = need - (count in buckets > b)   (>= 1)
__device__ __forceinline__ void wave_suffix_select(const int* hist, int need,
                                                   int lane, int* out_b,
                                                   int* out_rem) {
  int sm = 0;
  const int bb = lane * 64;
  for (int i = 0; i < 64; ++i) sm += hist[bb + i];
  int sfx = sm;
#pragma unroll
  for (int d = 1; d < 64; d <<= 1) {
    int t = __shfl_down(sfx, d);
    if (lane + d < 64) sfx += t;
  }
  unsigned long long mk = __ballot(sfx >= need);
  const int cstar = 63 - __builtin_clzll(mk);
  const int aboveC = __shfl(sfx, cstar) - __shfl(sm, cstar);
  int h = hist[cstar * 64 + lane];
  int sfx2 = h;
#pragma unroll
  for (int d = 1; d < 64; d <<= 1) {
    int t = __shfl_down(sfx2, d);
    if (lane + d < 64) sfx2 += t;
  }
  unsigned long long mk2 = __ballot(aboveC + sfx2 >= need);
  const int boff = 63 - __builtin_clzll(mk2);
  const int aboveB = aboveC + __shfl(sfx2, boff) - __shfl(h, boff);
  if (lane == 0) {
    *out_b = cstar * 64 + boff;
    *out_rem = need - aboveB;
  }
}

// ====== Kernel AZ: transform + chunk-max + slice-max + zero-fill probs ======
__global__ __launch_bounds__(256) void kAZ_chunkmax(
    const float* __restrict__ logits, const int* __restrict__ toks,
    const float* __restrict__ temps, const float* __restrict__ rps,
    unsigned short* __restrict__ ws_cmax, float* __restrict__ ws_bmax,
    float* __restrict__ probs) {
  __shared__ unsigned int s_seen[VW];
  __shared__ float s_red[4];
  const int row = blockIdx.x >> 3;
  const int slice = blockIdx.x & 7;
  const int tid = threadIdx.x;
  const int lane = tid & 63;
  const int wid = tid >> 6;
  const float rp = rps[row];
  const float irp = 1.0f / rp;
  const float itemp = 1.0f / temps[row];
  const size_t base = (size_t)row * V;
  const float4* __restrict__ lg4 = reinterpret_cast<const float4*>(logits + base);
  vfloat4* __restrict__ pr4 = reinterpret_cast<vfloat4*>(probs + base);

  for (int i = tid; i < VW; i += 256) s_seen[i] = 0u;
  __syncthreads();
  for (int i = tid; i < W; i += 256) {
    int tok = toks[row * W + i];
    if (tok >= 0 && tok < V) atomicOr(&s_seen[tok >> 5], 1u << (tok & 31));
  }
  __syncthreads();

  float lmax = -INFINITY;
  const int q0 = slice * SL4;
  const vfloat4 z4 = (vfloat4){0.0f, 0.0f, 0.0f, 0.0f};
  for (int qi = tid; qi < SL4; qi += 256) {
    const int q = q0 + qi;
    float4 x4 = lg4[q];
    pr4[q] = z4;
    float xs[4] = {x4.x, x4.y, x4.z, x4.w};
    const int j0 = q * 4;
    const int sh = j0 & 31;
    unsigned long long ww = (unsigned long long)s_seen[j0 >> 5] |
                            ((unsigned long long)s_seen[(j0 + 3) >> 5] << 32);
    unsigned int kmax = 0u;
#pragma unroll
    for (int e = 0; e < 4; ++e) {
      float x = xform(xs[e], (ww >> (sh + e)) & 1ull, rp, irp, itemp);
      lmax = fmaxf(lmax, x);
      unsigned int ky = fkey(x);
      kmax = kmax > ky ? kmax : ky;
    }
    unsigned int o;
    o = __shfl_xor(kmax, 1); kmax = kmax > o ? kmax : o;
    o = __shfl_xor(kmax, 2); kmax = kmax > o ? kmax : o;
    if ((lane & 3) == 0) ws_cmax[row * NCHUNK + (q >> 2)] = (unsigned short)(kmax >> 16);
  }
#pragma unroll
  for (int d = 32; d > 0; d >>= 1) lmax = fmaxf(lmax, __shfl_xor(lmax, d));
  if (lane == 0) s_red[wid] = lmax;
  __syncthreads();
  if (tid == 0) {
    float mm = fmaxf(fmaxf(s_red[0], s_red[1]), fmaxf(s_red[2], s_red[3]));
    ws_bmax[row * NSLICE + slice] = mm;
  }
}

// ====== Kernel B: select + gather + radix-kth + compact + sort + top-p + sample ======
__global__ __launch_bounds__(1024) void kB_select(
    const float* __restrict__ logits, const int* __restrict__ toks,
    const float* __restrict__ temps, const float* __restrict__ topps,
    const int* __restrict__ topks, const float* __restrict__ rps,
    const unsigned short* __restrict__ ws_cmax, const float* __restrict__ ws_bmax,
    float* __restrict__ out_ids, float* __restrict__ probs) {
  __shared__ unsigned long long s_key[CAP];        // 32 KB; hosts b0-hist pre-gather
  __shared__ __align__(16) unsigned char s_bufA[16384]; // seen (pre) / radix hist (post)
  __shared__ __align__(16) unsigned char s_bufB[16384]; // cmax16 (pre) / survivors (post)
  __shared__ float s_e2[CAPS];                     // 8 KB survivor exp / final probs
  __shared__ float s_q2[CAPS];                     // 8 KB survivor p = e/denom
  __shared__ unsigned char s_keep[CAPS];           // 2 KB
  __shared__ float s_wredf[16];
  __shared__ int s_wredi[16];
  __shared__ float s_mv, s_dn1, s_dn2;
  __shared__ int s_b0, s_cnt, s_scnt, s_selb, s_selrem;

  int* s_hist0 = (int*)s_key;                      // b0 hist (dead before keys)
  unsigned int* s_seen = (unsigned int*)s_bufA;
  int* s_hist = (int*)s_bufA;                      // radix hists (seen dead post-gather)
  unsigned short* s_cmax16 = (unsigned short*)s_bufB;
  unsigned long long* s_key2 = (unsigned long long*)s_bufB;

  const int row = blockIdx.x;
  const int tid = threadIdx.x;
  const int lane = tid & 63;
  const int wid = tid >> 6;
  const float rp = rps[row];
  const float irp = 1.0f / rp;
  const float itemp = 1.0f / temps[row];
  const float topp = topps[row];
  const int k = topks[row];
  const size_t base = (size_t)row * V;
  const float4* __restrict__ lg4 = reinterpret_cast<const float4*>(logits + base);
  float* __restrict__ prow = probs + base;

  // init: seen=0, b0-hist=0, cmax->LDS
  for (int i = tid; i < VW; i += 1024) s_seen[i] = 0u;
  for (int i = tid; i < 4096; i += 1024) s_hist0[i] = 0;
  {
    const unsigned int* cm32 = reinterpret_cast<const unsigned int*>(ws_cmax + row * NCHUNK);
    unsigned int* sc32 = reinterpret_cast<unsigned int*>(s_cmax16);
    for (int i = tid; i < NCHUNK / 2; i += 1024) sc32[i] = cm32[i];
  }
  __syncthreads();
  for (int i = tid; i < W; i += 1024) {
    int tok = toks[row * W + i];
    if (tok >= 0 && tok < V) atomicOr(&s_seen[tok >> 5], 1u << (tok & 31));
  }
  __syncthreads();

  // chunk-max histogram (selects gather bound b0)
  for (int i = tid; i < NCHUNK; i += 1024)
    atomicAdd(&s_hist0[s_cmax16[i] >> 4], 1);
  __syncthreads();

  if (wid == 1 && lane == 0) {
    float mm = ws_bmax[row * NSLICE];
    for (int i = 1; i < NSLICE; ++i) mm = fmaxf(mm, ws_bmax[row * NSLICE + i]);
    s_mv = mm;
  }
  if (wid == 0) {
    wave_suffix_select(s_hist0, k, lane, &s_b0, &s_selrem);
    if (lane == 0) s_cnt = 0;
  }
  __syncthreads();
  const int b0 = s_b0;

  // gather candidates as u64 keys (fkey<<32 | idx); 1 atomic per wave-iter
  const unsigned int fk0 = ((unsigned int)b0) << 20;
  const int c16 = b0 << 4;
  for (int qb = 0; qb < V4; qb += 1024) {
    const int q = qb + tid;
    const bool act = (q < V4) && ((int)s_cmax16[q >> 2] >= c16);
    unsigned int ks[4];
    bool pr[4] = {false, false, false, false};
    const int j0 = q * 4;
    if (act) {
      float4 x4 = lg4[q];
      float raw[4] = {x4.x, x4.y, x4.z, x4.w};
      const int sh = j0 & 31;
      unsigned long long ww = (unsigned long long)s_seen[j0 >> 5] |
                              ((unsigned long long)s_seen[(j0 + 3) >> 5] << 32);
#pragma unroll
      for (int e = 0; e < 4; ++e) {
        float x = xform(raw[e], (ww >> (sh + e)) & 1ull, rp, irp, itemp);
        ks[e] = fkey(x);
        pr[e] = (ks[e] >= fk0);
      }
    }
    int cnt = (int)pr[0] + (int)pr[1] + (int)pr[2] + (int)pr[3];
    int inc = cnt;
#pragma unroll
    for (int d = 1; d < 64; d <<= 1) {
      int t = __shfl_up(inc, d);
      if (lane >= d) inc += t;
    }
    const int total = __shfl(inc, 63);
    if (total) {
      int basep = 0;
      if (lane == 0) basep = atomicAdd(&s_cnt, total);
      basep = __shfl(basep, 0);
      int off = basep + inc - cnt;
#pragma unroll
      for (int e = 0; e < 4; ++e) {
        if (pr[e]) {
          if (off < CAP)
            s_key[off] = ((unsigned long long)ks[e] << 32) | (unsigned int)(j0 + e);
          ++off;
        }
      }
    }
  }
  __syncthreads();
  int G = s_cnt;
  if (G > CAP) G = CAP;
  const int kk = k > G ? G : k;

  // ---- exact kth via 3-pass LDS radix over candidate fkeys (12/12/8 bits) ----
  for (int i = tid; i < 4096; i += 1024) s_hist[i] = 0;
  __syncthreads();
  for (int i = tid; i < G; i += 1024)
    atomicAdd(&s_hist[(unsigned int)(s_key[i] >> 52)], 1);  // fkey>>20
  __syncthreads();
  if (wid == 0) wave_suffix_select(s_hist, kk, lane, &s_selb, &s_selrem);
  __syncthreads();
  const unsigned int b1 = (unsigned int)s_selb;
  const int n1 = s_selrem;
  for (int i = tid; i < 4096; i += 1024) s_hist[i] = 0;
  __syncthreads();
  for (int i = tid; i < G; i += 1024) {
    unsigned int hi = (unsigned int)(s_key[i] >> 32);
    if ((hi >> 20) == b1) atomicAdd(&s_hist[(hi >> 8) & 0xFFFu], 1);
  }
  __syncthreads();
  if (wid == 0) wave_suffix_select(s_hist, n1, lane, &s_selb, &s_selrem);
  __syncthreads();
  const unsigned int b2 = (unsigned int)s_selb;
  const int n2 = s_selrem;
  const unsigned int pre24 = (b1 << 12) | b2;
  for (int i = tid; i < 4096; i += 1024) s_hist[i] = 0;
  __syncthreads();
  for (int i = tid; i < G; i += 1024) {
    unsigned int hi = (unsigned int)(s_key[i] >> 32);
    if ((hi >> 8) == pre24) atomicAdd(&s_hist[hi & 0xFFu], 1);
  }
  __syncthreads();
  if (wid == 0) {
    wave_suffix_select(s_hist, n2, lane, &s_selb, &s_selrem);
    if (lane == 0) s_scnt = 0;
  }
  __syncthreads();
  const unsigned int kthkey = (pre24 << 8) | (unsigned int)s_selb;

  // ---- compact survivors (fkey >= kthkey) into s_key2 (cmax16 dead) ----
  __syncthreads();   // ensure all cmax16 reads (gather) done before overwrite
  for (int ib = 0; ib < G; ib += 1024) {
    const int i = ib + tid;
    const bool p = (i < G) && ((unsigned int)(s_key[i] >> 32) >= kthkey);
    unsigned long long mask = __ballot(p);
    if (!mask) continue;
    int basep = 0;
    if (lane == 0) basep = atomicAdd(&s_scnt, __popcll(mask));
    basep = __shfl(basep, 0);
    if (p) {
      int pos = basep + __popcll(mask & ((1ull << lane) - 1ull));
      if (pos < CAPS) s_key2[pos] = s_key[i];
    }
  }
  __syncthreads();
  int S = s_scnt;
  if (S > CAPS) S = CAPS;

  // ---- bitonic sort survivors ascending (u64 == (value, index) order) ----
  int np2 = 2;
  while (np2 < S) np2 <<= 1;
  for (int i = S + tid; i < np2; i += 1024) s_key2[i] = ~0ull;
  __syncthreads();
  for (int size = 2; size <= np2; size <<= 1) {
    for (int stride = size >> 1; stride > 0; stride >>= 1) {
      for (int t2 = tid; t2 < (np2 >> 1); t2 += 1024) {
        int pos = 2 * t2 - (t2 & (stride - 1));
        int qq = pos + stride;
        bool up = ((pos & size) == 0);
        unsigned long long a = s_key2[pos], b = s_key2[qq];
        if ((a > b) == up) { s_key2[pos] = b; s_key2[qq] = a; }
      }
      __syncthreads();
    }
  }

  // ---- softmax denom over survivors ----
  const float m = s_mv;
  float part = 0.0f;
  for (int i = tid; i < S; i += 1024) {
    float x = ikey((unsigned int)(s_key2[i] >> 32));
    float e = expf(x - m);
    s_e2[i] = e;
    part += e;
  }
#pragma unroll
  for (int d = 32; d > 0; d >>= 1) part += __shfl_xor(part, d);
  if (lane == 0) s_wredf[wid] = part;
  __syncthreads();
  if (tid == 0) {
    float s = 0.0f;
    for (int i = 0; i < 16; ++i) s += s_wredf[i];
    s_dn1 = s;
  }
  __syncthreads();
  const float denom = s_dn1;

  // precompute p_i = e_i/denom in parallel (identical rounding to inline)
  for (int i = tid; i < S; i += 1024) s_q2[i] = s_e2[i] / denom;
  __syncthreads();

  // ---- serial fp32 cumsum (pure add chain) + top-p mask, last kept ----
  if (tid == 0) {
    const float cut = 1.0f - topp;
    float cs = 0.0f;
    int i = 0;
    for (; i + 16 <= S; i += 16) {
      vfloat4 a = *(const vfloat4*)&s_q2[i];
      vfloat4 b = *(const vfloat4*)&s_q2[i + 4];
      vfloat4 c = *(const vfloat4*)&s_q2[i + 8];
      vfloat4 d = *(const vfloat4*)&s_q2[i + 12];
      unsigned int w0, w1, w2, w3;
      cs += a.x; w0  = (cs <= cut) ? 0u : 1u;
      cs += a.y; w0 |= ((cs <= cut) ? 0u : 1u) << 8;
      cs += a.z; w0 |= ((cs <= cut) ? 0u : 1u) << 16;
      cs += a.w; w0 |= ((cs <= cut) ? 0u : 1u) << 24;
      cs += b.x; w1  = (cs <= cut) ? 0u : 1u;
      cs += b.y; w1 |= ((cs <= cut) ? 0u : 1u) << 8;
      cs += b.z; w1 |= ((cs <= cut) ? 0u : 1u) << 16;
      cs += b.w; w1 |= ((cs <= cut) ? 0u : 1u) << 24;
      cs += c.x; w2  = (cs <= cut) ? 0u : 1u;
      cs += c.y; w2 |= ((cs <= cut) ? 0u : 1u) << 8;
      cs += c.z; w2 |= ((cs <= cut) ? 0u : 1u) << 16;
      cs += c.w; w2 |= ((cs <= cut) ? 0u : 1u) << 24;
      cs += d.x; w3  = (cs <= cut) ? 0u : 1u;
      cs += d.y; w3 |= ((cs <= cut) ? 0u : 1u) << 8;
      cs += d.z; w3 |= ((cs <= cut) ? 0u : 1u) << 16;
      cs += d.w; w3 |= ((cs <= cut) ? 0u : 1u) << 24;
      *(unsigned int*)&s_keep[i] = w0;
      *(unsigned int*)&s_keep[i + 4] = w1;
      *(unsigned int*)&s_keep[i + 8] = w2;
      *(unsigned int*)&s_keep[i + 12] = w3;
    }
    for (; i < S; ++i) {
      cs += s_q2[i];
      s_keep[i] = (cs <= cut) ? 0 : 1;
    }
    s_keep[S - 1] = 1;
  }
  __syncthreads();

  // ---- final denom over kept ----
  part = 0.0f;
  for (int i = tid; i < S; i += 1024)
    if (s_keep[i]) part += s_e2[i];
#pragma unroll
  for (int d = 32; d > 0; d >>= 1) part += __shfl_xor(part, d);
  if (lane == 0) s_wredf[wid] = part;
  __syncthreads();
  if (tid == 0) {
    float s = 0.0f;
    for (int i = 0; i < 16; ++i) s += s_wredf[i];
    s_dn2 = s;
  }
  __syncthreads();
  const float denom2 = s_dn2;

  for (int i = tid; i < S; i += 1024)
    s_e2[i] = s_keep[i] ? (s_e2[i] / denom2) : 0.0f;
  __syncthreads();

  // ---- Gumbel argmax over kept survivors ----
  float bs = -INFINITY;
  int bi = 0x7FFFFFFF;
  for (int i = tid; i < S; i += 1024) {
    if (!s_keep[i]) continue;
    unsigned long long kv = s_key2[i];
    int j = (int)(kv & 0xFFFFFFFFull);
    float x = ikey((unsigned int)(kv >> 32));
    unsigned int t = (unsigned int)(row * V) + (unsigned int)j;
    unsigned int bb = tf_bits(t);
    float u = __uint_as_float((bb >> 9) | 0x3f800000u) - 1.0f;
    if (u < TINYF) u = TINYF;
    float g = -logf(-logf(u));
    float sc = x + g;
    if (sc > bs || (sc == bs && j < bi)) { bs = sc; bi = j; }
  }

  // ---- scatter nonzero probs (zeros already laid down by kAZ) ----
  for (int i = tid; i < S; i += 1024) {
    int j = (int)(s_key2[i] & 0xFFFFFFFFull);
    prow[j] = s_e2[i];
  }

  // ---- argmax reduce -> sampled id ----
#pragma unroll
  for (int d = 32; d > 0; d >>= 1) {
    float ov = __shfl_down(bs, d);
    int oi = __shfl_down(bi, d);
    if (ov > bs || (ov == bs && oi < bi)) { bs = ov; bi = oi; }
  }
  if (lane == 0) { s_wredf[wid] = bs; s_wredi[wid] = bi; }
  __syncthreads();
  if (tid == 0) {
    float bb = s_wredf[0];
    int bj = s_wredi[0];
    for (int i = 1; i < 16; ++i) {
      if (s_wredf[i] > bb || (s_wredf[i] == bb && s_wredi[i] < bj)) {
        bb = s_wredf[i];
        bj = s_wredi[i];
      }
    }
    out_ids[row] = (float)bj;
  }
}

// ================== Fallback: monolithic kernel (ws too small) ==================
__global__ __launch_bounds__(1024, 1) void sampler_mono(
    const float* __restrict__ logits, const int* __restrict__ toks,
    const float* __restrict__ temps, const float* __restrict__ topps,
    const int* __restrict__ topks, const float* __restrict__ rps,
    float* __restrict__ out_ids, float* __restrict__ probs) {
  __shared__ unsigned int s_seen[VW];
  __shared__ int s_hist[4096];
  __shared__ unsigned short s_cmax16[NCHUNK];
  __shared__ float s_sval[CAPM];
  __shared__ int s_sidx[CAPM];
  __shared__ float s_e[CAPM];
  __shared__ unsigned char s_keep[CAPM];
  __shared__ float s_wredf[16];
  __shared__ int s_wredi[16];
  __shared__ float s_m, s_denom, s_denom2;
  __shared__ int s_b0, s_cnt, s_p0;

  const int row = blockIdx.x;
  const int tid = threadIdx.x;
  const int lane = tid & 63;
  const int wid = tid >> 6;
  const float rp = rps[row];
  const float irp = 1.0f / rp;
  const float itemp = 1.0f / temps[row];
  const float topp = topps[row];
  const int k = topks[row];
  const size_t base = (size_t)row * V;
  const float4* __restrict__ lg4 = reinterpret_cast<const float4*>(logits + base);
  vfloat4* __restrict__ pr4 = reinterpret_cast<vfloat4*>(probs + base);

  for (int i = tid; i < VW; i += 1024) s_seen[i] = 0u;
  for (int i = tid; i < 4096; i += 1024) s_hist[i] = 0;
  __syncthreads();
  for (int i = tid; i < W; i += 1024) {
    int tok = toks[row * W + i];
    if (tok >= 0 && tok < V) atomicOr(&s_seen[tok >> 5], 1u << (tok & 31));
  }
  __syncthreads();

  float lmax = -INFINITY;
  for (int qb = 0; qb < V4; qb += 1024) {
    const int q = qb + tid;
    unsigned int kmax = 0u;
    if (q < V4) {
      float4 x4 = lg4[q];
      float xs[4] = {x4.x, x4.y, x4.z, x4.w};
      const int j0 = q * 4;
      const int sh = j0 & 31;
      unsigned long long ww = (unsigned long long)s_seen[j0 >> 5] |
                              ((unsigned long long)s_seen[(j0 + 3) >> 5] << 32);
#pragma unroll
      for (int e = 0; e < 4; ++e) {
        float x = xform(xs[e], (ww >> (sh + e)) & 1ull, rp, irp, itemp);
        lmax = fmaxf(lmax, x);
        unsigned int ky = fkey(x);
        kmax = kmax > ky ? kmax : ky;
      }
    }
    unsigned int o;
    o = __shfl_xor(kmax, 1); kmax = kmax > o ? kmax : o;
    o = __shfl_xor(kmax, 2); kmax = kmax > o ? kmax : o;
    if (((lane & 3) == 0) && (q < V4)) s_cmax16[q >> 2] = (unsigned short)(kmax >> 16);
  }
#pragma unroll
  for (int d = 32; d > 0; d >>= 1) lmax = fmaxf(lmax, __shfl_xor(lmax, d));
  if (lane == 0) s_wredf[wid] = lmax;
  __syncthreads();
  for (int i = tid; i < NCHUNK; i += 1024)
    atomicAdd(&s_hist[s_cmax16[i] >> 4], 1);
  __syncthreads();
  if (wid == 1 && lane == 0) {
    float mm = s_wredf[0];
    for (int i = 1; i < 16; ++i) mm = fmaxf(mm, s_wredf[i]);
    s_m = mm;
  }
  if (wid == 0) {
    int sm = 0;
    const int bb = lane * 64;
    for (int i = 0; i < 64; ++i) sm += s_hist[bb + i];
    int sfx = sm;
#pragma unroll
    for (int d = 1; d < 64; d <<= 1) {
      int t = __shfl_down(sfx, d);
      if (lane + d < 64) sfx += t;
    }
    unsigned long long mk = __ballot(sfx >= k);
    const int cstar = 63 - __builtin_clzll(mk);
    const int above = __shfl(sfx, cstar) - __shfl(sm, cstar);
    int h = s_hist[cstar * 64 + lane];
    int sfx2 = h;
#pragma unroll
    for (int d = 1; d < 64; d <<= 1) {
      int t = __shfl_down(sfx2, d);
      if (lane + d < 64) sfx2 += t;
    }
    unsigned long long mk2 = __ballot(above + sfx2 >= k);
    const int boff = 63 - __builtin_clzll(mk2);
    if (lane == 0) { s_b0 = cstar * 64 + boff; s_cnt = 0; }
  }
  __syncthreads();
  const int b0 = s_b0;
  const unsigned int fk0 = ((unsigned int)b0) << 20;
  const int c16 = b0 << 4;
  for (int qb = 0; qb < V4; qb += 1024) {
    const int q = qb + tid;
    const bool act = (q < V4) && ((int)s_cmax16[q >> 2] >= c16);
    float xs[4];
    bool pr[4] = {false, false, false, false};
    const int j0 = q * 4;
    if (act) {
      float4 x4 = lg4[q];
      float raw[4] = {x4.x, x4.y, x4.z, x4.w};
      const int sh = j0 & 31;
      unsigned long long ww = (unsigned long long)s_seen[j0 >> 5] |
                              ((unsigned long long)s_seen[(j0 + 3) >> 5] << 32);
#pragma unroll
      for (int e = 0; e < 4; ++e) {
        xs[e] = xform(raw[e], (ww >> (sh + e)) & 1ull, rp, irp, itemp);
        pr[e] = (fkey(xs[e]) >= fk0);
      }
    }
#pragma unroll
    for (int e = 0; e < 4; ++e) {
      unsigned long long mask = __ballot(pr[e]);
      if (!mask) continue;
      int basep = 0;
      if (lane == 0) basep = atomicAdd(&s_cnt, __popcll(mask));
      basep = __shfl(basep, 0);
      if (pr[e]) {
        int pos = basep + __popcll(mask & ((1ull << lane) - 1ull));
        if (pos < CAPM) { s_sval[pos] = xs[e]; s_sidx[pos] = j0 + e; }
      }
    }
  }
  __syncthreads();
  int G = s_cnt;
  if (G > CAPM) G = CAPM;
  int np2 = 2;
  while (np2 < G) np2 <<= 1;
  for (int i = G + tid; i < np2; i += 1024) {
    s_sval[i] = INFINITY;
    s_sidx[i] = 0x7FFFFFFF;
  }
  __syncthreads();
  for (int size = 2; size <= np2; size <<= 1) {
    for (int stride = size >> 1; stride > 0; stride >>= 1) {
      for (int t2 = tid; t2 < (np2 >> 1); t2 += 1024) {
        int pos = 2 * t2 - (t2 & (stride - 1));
        int qq = pos + stride;
        bool up = ((pos & size) == 0);
        float v1 = s_sval[pos], v2 = s_sval[qq];
        int i1 = s_sidx[pos], i2 = s_sidx[qq];
        bool gt = (v1 > v2) || (v1 == v2 && i1 > i2);
        if (gt == up) {
          s_sval[pos] = v2; s_sval[qq] = v1;
          s_sidx[pos] = i2; s_sidx[qq] = i1;
        }
      }
      __syncthreads();
    }
  }
  const int kk = k > G ? G : k;
  const float kth = s_sval[G - kk];
  const float m = s_m;
  for (int i = tid; i < G; i += 1024) {
    if (s_sval[i] >= kth && (i == 0 || s_sval[i - 1] < kth)) s_p0 = i;
  }
  __syncthreads();
  const int p0 = s_p0;
  float part = 0.0f;
  for (int i = p0 + tid; i < G; i += 1024) {
    float e = expf(s_sval[i] - m);
    s_e[i] = e;
    part += e;
  }
#pragma unroll
  for (int d = 32; d > 0; d >>= 1) part += __shfl_xor(part, d);
  if (lane == 0) s_wredf[wid] = part;
  __syncthreads();
  if (tid == 0) {
    float s = 0.0f;
    for (int i = 0; i < 16; ++i) s += s_wredf[i];
    s_denom = s;
  }
  __syncthreads();
  const float denom = s_denom;
  if (tid == 0) {
    const float cut = 1.0f - topp;
    float cs = 0.0f;
    for (int i = p0; i < G; ++i) {
      cs += s_e[i] / denom;
      s_keep[i] = (cs <= cut) ? 0 : 1;
    }
    s_keep[G - 1] = 1;
  }
  __syncthreads();
  part = 0.0f;
  for (int i = p0 + tid; i < G; i += 1024)
    if (s_keep[i]) part += s_e[i];
#pragma unroll
  for (int d = 32; d > 0; d >>= 1) part += __shfl_xor(part, d);
  if (lane == 0) s_wredf[wid] = part;
  __syncthreads();
  if (tid == 0) {
    float s = 0.0f;
    for (int i = 0; i < 16; ++i) s += s_wredf[i];
    s_denom2 = s;
  }
  __syncthreads();
  const float denom2 = s_denom2;
  for (int i = p0 + tid; i < G; i += 1024)
    s_e[i] = s_keep[i] ? (s_e[i] / denom2) : 0.0f;
  __syncthreads();
  float bs = -INFINITY;
  int bi = 0x7FFFFFFF;
  for (int i = p0 + tid; i < G; i += 1024) {
    if (!s_keep[i]) continue;
    int j = s_sidx[i];
    unsigned int t = (unsigned int)(row * V) + (unsigned int)j;
    unsigned int bb = tf_bits(t);
    float u = __uint_as_float((bb >> 9) | 0x3f800000u) - 1.0f;
    if (u < TINYF) u = TINYF;
    float g = -logf(-logf(u));
    float sc = s_sval[i] + g;
    if (sc > bs || (sc == bs && j < bi)) { bs = sc; bi = j; }
  }
  const unsigned int kkey = fkey(kth);
  const int k16 = (int)(kkey >> 16);
  for (int q = tid; q < V4; q += 1024) {
    vfloat4 o = (vfloat4){0.0f, 0.0f, 0.0f, 0.0f};
    if ((int)s_cmax16[q >> 2] >= k16) {
      float4 x4 = lg4[q];
      float raw[4] = {x4.x, x4.y, x4.z, x4.w};
      float os[4];
      const int j0 = q * 4;
      const int sh = j0 & 31;
      unsigned long long ww = (unsigned long long)s_seen[j0 >> 5] |
                              ((unsigned long long)s_seen[(j0 + 3) >> 5] << 32);
#pragma unroll
      for (int e = 0; e < 4; ++e) {
        float x = xform(raw[e], (ww >> (sh + e)) & 1ull, rp, irp, itemp);
        float pr = 0.0f;
        if (x >= kth) {
          int j = j0 + e;
          int lo = p0, hi = G;
          while (lo < hi) {
            int mid = (lo + hi) >> 1;
            float v = s_sval[mid];
            int id = s_sidx[mid];
            if (v < x || (v == x && id < j)) lo = mid + 1; else hi = mid;
          }
          pr = s_e[lo];
        }
        os[e] = pr;
      }
      o.x = os[0]; o.y = os[1]; o.z = os[2]; o.w = os[3];
    }
    pr4[q] = o;
  }
#pragma unroll
  for (int d = 32; d > 0; d >>= 1) {
    float ov = __shfl_down(bs, d);
    int oi = __shfl_down(bi, d);
    if (ov > bs || (ov == bs && oi < bi)) { bs = ov; bi = oi; }
  }
  if (lane == 0) { s_wredf[wid] = bs; s_wredi[wid] = bi; }
  __syncthreads();
  if (tid == 0) {
    float bb = s_wredf[0];
    int bj = s_wredi[0];
    for (int i = 1; i < 16; ++i) {
      if (s_wredf[i] > bb || (s_wredf[i] == bb && s_wredi[i] < bj)) {
        bb = s_wredf[i];
        bj = s_wredi[i];
      }
    }
    out_ids[row] = (float)bj;
  }
}

extern "C" void kernel_launch(void* const* d_in, const int* in_sizes, int n_in,
                              void* d_out, int out_size, void* d_ws, size_t ws_size,
                              hipStream_t stream) {
  (void)in_sizes; (void)out_size;
  if (n_in < 6) return;
  const float* logits = (const float*)d_in[0];
  const int* toks = (const int*)d_in[1];
  const float* temps = (const float*)d_in[2];
  const float* topps = (const float*)d_in[3];
  const int* topks = (const int*)d_in[4];
  const float* rps = (const float*)d_in[5];
  float* out = (float*)d_out;            // [0,256): ids as float; [256,...): probs
  float* probs = out + NROWS;

  if (ws_size >= WS_NEED && d_ws != nullptr) {
    char* w = (char*)d_ws;
    unsigned short* ws_cmax = (unsigned short*)(w + WS_CMAX);
    float* ws_bmax = (float*)(w + WS_BMAX);
    kAZ_chunkmax<<<dim3(NROWS * NSLICE), dim3(256), 0, stream>>>(
        logits, toks, temps, rps, ws_cmax, ws_bmax, probs);
    kB_select<<<dim3(NROWS), dim3(1024), 0, stream>>>(
        logits, toks, temps, topps, topks, rps, ws_cmax, ws_bmax, out, probs);
  } else {
    sampler_mono<<<dim3(NROWS), dim3(1024), 0, stream>>>(
        logits, toks, temps, topps, topks, rps, out, probs);
  }
}

// Round 9
// 119.855 us; speedup vs baseline: 2.0804x; 1.0962x over previous
//
#include <hip/hip_runtime.h>

#define V 128000
#define V4 (V / 4)
#define NCHUNK (V / 16)      // 8000 chunk-max entries (16 elems each)
#define NROWS 256
#define NSLICE 8
#define SL4 (V4 / NSLICE)    // 4000 float4 per slice
#define W 200
#define VW (V / 32)          // 4000 words of seen-bitmask
#define CAP 4096             // candidate capacity
#define CAPS 2048            // survivor capacity
#define CAPM 8192            // mono-kernel capacity
#define TINYF 1.17549435e-38f
#define HIDX(b) ((b) + ((b) >> 5))   // padded hist index (4096 -> 4224 slots)
#define HSZ 4224

// ---- d_ws layout ----
#define WS_CMAX   0u          // u16[256][8000]
#define WS_BMAX   4104192u    // float[256][8]
#define WS_NEED   16777216u

typedef float vfloat4 __attribute__((ext_vector_type(4)));

__device__ __forceinline__ unsigned int fkey(float x) {
  unsigned int u = __float_as_uint(x);
  return (u & 0x80000000u) ? ~u : (u | 0x80000000u);
}
__device__ __forceinline__ float ikey(unsigned int k) {
  unsigned int u = (k & 0x80000000u) ? (k & 0x7FFFFFFFu) : ~k;
  return __uint_as_float(u);
}

// ---- jax threefry2x32, partitionable: counter=(0,t), key=(0,42), fold=xor ----
__device__ __forceinline__ unsigned int tf_bits(unsigned int t) {
  const unsigned int k0 = 0u, k1 = 42u;
  const unsigned int ks2 = k0 ^ k1 ^ 0x1BD11BDAu;
  unsigned int x0 = 0u + k0, x1 = t + k1;
  const unsigned int ksArr[3] = {k0, k1, ks2};
  const int RA[4] = {13, 15, 26, 6};
  const int RB[4] = {17, 29, 16, 24};
#pragma unroll
  for (int i = 0; i < 5; ++i) {
#pragma unroll
    for (int j = 0; j < 4; ++j) {
      int r = (i & 1) ? RB[j] : RA[j];
      x0 += x1;
      x1 = (x1 << r) | (x1 >> (32 - r));
      x1 ^= x0;
    }
    x0 += ksArr[(i + 1) % 3];
    x1 += ksArr[(i + 2) % 3] + (unsigned int)(i + 1);
  }
  return x0 ^ x1;
}

__device__ __forceinline__ float xform(float x, bool seen, float rp, float irp,
                                        float itemp) {
  if (seen) x = (x > 0.0f) ? x * irp : x * rp;
  return x * itemp;
}

// Wave-parallel suffix select over a padded 4096-bucket histogram (one wave).
// Finds highest bucket b with (count in buckets >= b) >= need; rem unused ok.
__device__ __forceinline__ void wave_suffix_select_p(const int* hist, int need,
                                                     int lane, int* out_b,
                                                     int* out_rem) {
  int sm = 0;
  const int bb = lane * 64;
  for (int i = 0; i < 64; ++i) sm += hist[HIDX(bb + i)];
  int sfx = sm;
#pragma unroll
  for (int d = 1; d < 64; d <<= 1) {
    int t = __shfl_down(sfx, d);
    if (lane + d < 64) sfx += t;
  }
  unsigned long long mk = __ballot(sfx >= need);
  const int cstar = 63 - __builtin_clzll(mk);
  const int aboveC = __shfl(sfx, cstar) - __shfl(sm, cstar);
  int h = hist[HIDX(cstar * 64 + lane)];
  int sfx2 = h;
#pragma unroll
  for (int d = 1; d < 64; d <<= 1) {
    int t = __shfl_down(sfx2, d);
    if (lane + d < 64) sfx2 += t;
  }
  unsigned long long mk2 = __ballot(aboveC + sfx2 >= need);
  const int boff = 63 - __builtin_clzll(mk2);
  const int aboveB = aboveC + __shfl(sfx2, boff) - __shfl(h, boff);
  if (lane == 0) {
    *out_b = cstar * 64 + boff;
    *out_rem = need - aboveB;
  }
}

// ====== Kernel AZ: transform + chunk-max + slice-max + zero-fill probs ======
__global__ __launch_bounds__(256) void kAZ_chunkmax(
    const float* __restrict__ logits, const int* __restrict__ toks,
    const float* __restrict__ temps, const float* __restrict__ rps,
    unsigned short* __restrict__ ws_cmax, float* __restrict__ ws_bmax,
    float* __restrict__ probs) {
  __shared__ unsigned int s_seen[VW];
  __shared__ float s_red[4];
  const int row = blockIdx.x >> 3;
  const int slice = blockIdx.x & 7;
  const int tid = threadIdx.x;
  const int lane = tid & 63;
  const int wid = tid >> 6;
  const float rp = rps[row];
  const float irp = 1.0f / rp;
  const float itemp = 1.0f / temps[row];
  const size_t base = (size_t)row * V;
  const float4* __restrict__ lg4 = reinterpret_cast<const float4*>(logits + base);
  vfloat4* __restrict__ pr4 = reinterpret_cast<vfloat4*>(probs + base);

  for (int i = tid; i < VW; i += 256) s_seen[i] = 0u;
  __syncthreads();
  for (int i = tid; i < W; i += 256) {
    int tok = toks[row * W + i];
    if (tok >= 0 && tok < V) atomicOr(&s_seen[tok >> 5], 1u << (tok & 31));
  }
  __syncthreads();

  float lmax = -INFINITY;
  const int q0 = slice * SL4;
  const vfloat4 z4 = (vfloat4){0.0f, 0.0f, 0.0f, 0.0f};
  for (int qi = tid; qi < SL4; qi += 256) {
    const int q = q0 + qi;
    float4 x4 = lg4[q];
    pr4[q] = z4;
    float xs[4] = {x4.x, x4.y, x4.z, x4.w};
    const int j0 = q * 4;
    const int sh = j0 & 31;
    unsigned long long ww = (unsigned long long)s_seen[j0 >> 5] |
                            ((unsigned long long)s_seen[(j0 + 3) >> 5] << 32);
    unsigned int kmax = 0u;
#pragma unroll
    for (int e = 0; e < 4; ++e) {
      float x = xform(xs[e], (ww >> (sh + e)) & 1ull, rp, irp, itemp);
      lmax = fmaxf(lmax, x);
      unsigned int ky = fkey(x);
      kmax = kmax > ky ? kmax : ky;
    }
    unsigned int o;
    o = __shfl_xor(kmax, 1); kmax = kmax > o ? kmax : o;
    o = __shfl_xor(kmax, 2); kmax = kmax > o ? kmax : o;
    if ((lane & 3) == 0) ws_cmax[row * NCHUNK + (q >> 2)] = (unsigned short)(kmax >> 16);
  }
#pragma unroll
  for (int d = 32; d > 0; d >>= 1) lmax = fmaxf(lmax, __shfl_xor(lmax, d));
  if (lane == 0) s_red[wid] = lmax;
  __syncthreads();
  if (tid == 0) {
    float mm = fmaxf(fmaxf(s_red[0], s_red[1]), fmaxf(s_red[2], s_red[3]));
    ws_bmax[row * NSLICE + slice] = mm;
  }
}

// ====== Kernel B: select + gather + 1-pass radix + counting sort + top-p + sample ======
__global__ __launch_bounds__(1024) void kB_select(
    const float* __restrict__ logits, const int* __restrict__ toks,
    const float* __restrict__ temps, const float* __restrict__ topps,
    const int* __restrict__ topks, const float* __restrict__ rps,
    const unsigned short* __restrict__ ws_cmax, const float* __restrict__ ws_bmax,
    float* __restrict__ out_ids, float* __restrict__ probs) {
  __shared__ unsigned long long s_key[CAP];             // 32 KB; chunk-hist / candidates / sorted
  __shared__ __align__(16) unsigned char s_bufA[HSZ*4]; // 16.9 KB; seen -> radix/count hist
  __shared__ __align__(16) unsigned char s_bufB[16384]; // 16 KB; cmax16 -> survivors
  __shared__ __align__(16) float s_e2[CAPS];            // 8 KB survivor exp / final probs
  __shared__ __align__(16) float s_q2[CAPS];            // 8 KB survivor p = e/denom
  __shared__ unsigned char s_keep[CAPS];                // 2 KB
  __shared__ float s_wredf[16];
  __shared__ int s_wredi[16];
  __shared__ float s_mv, s_dn1, s_dn2;
  __shared__ int s_b0, s_cnt, s_scnt, s_selb, s_selrem, s_p0v, s_maxpop;

  int* s_hist0 = (int*)s_key;                 // padded chunk hist (dead before keys)
  unsigned int* s_seen = (unsigned int*)s_bufA;
  int* s_hist = (int*)s_bufA;                 // padded radix/counting hist
  unsigned short* s_cmax16 = (unsigned short*)s_bufB;
  unsigned long long* s_key2 = (unsigned long long*)s_bufB;  // survivors (unsorted)
  unsigned long long* s_skey = s_key;         // sorted survivors (candidates dead)

  const int row = blockIdx.x;
  const int tid = threadIdx.x;
  const int lane = tid & 63;
  const int wid = tid >> 6;
  const float rp = rps[row];
  const float irp = 1.0f / rp;
  const float itemp = 1.0f / temps[row];
  const float topp = topps[row];
  const int k = topks[row];
  const size_t base = (size_t)row * V;
  const float4* __restrict__ lg4 = reinterpret_cast<const float4*>(logits + base);
  float* __restrict__ prow = probs + base;

  // init: seen=0, chunk-hist=0, cmax->LDS
  for (int i = tid; i < VW; i += 1024) s_seen[i] = 0u;
  for (int i = tid; i < HSZ; i += 1024) s_hist0[i] = 0;
  {
    const unsigned int* cm32 = reinterpret_cast<const unsigned int*>(ws_cmax + row * NCHUNK);
    unsigned int* sc32 = reinterpret_cast<unsigned int*>(s_cmax16);
    for (int i = tid; i < NCHUNK / 2; i += 1024) sc32[i] = cm32[i];
  }
  __syncthreads();
  for (int i = tid; i < W; i += 1024) {
    int tok = toks[row * W + i];
    if (tok >= 0 && tok < V) atomicOr(&s_seen[tok >> 5], 1u << (tok & 31));
  }
  for (int i = tid; i < NCHUNK; i += 1024)
    atomicAdd(&s_hist0[HIDX(s_cmax16[i] >> 4)], 1);
  __syncthreads();

  // bucket select b0 (wave 0); row max m (wave 1)
  if (wid == 1 && lane == 0) {
    float mm = ws_bmax[row * NSLICE];
    for (int i = 1; i < NSLICE; ++i) mm = fmaxf(mm, ws_bmax[row * NSLICE + i]);
    s_mv = mm;
  }
  if (wid == 0) {
    wave_suffix_select_p(s_hist0, k, lane, &s_b0, &s_selrem);
    if (lane == 0) s_cnt = 0;
  }
  __syncthreads();
  const int b0 = s_b0;

  // gather candidates as u64 keys (fkey<<32 | idx); 1 atomic per wave-iter
  const unsigned int fk0 = ((unsigned int)b0) << 20;
  const int c16 = b0 << 4;
  for (int qb = 0; qb < V4; qb += 1024) {
    const int q = qb + tid;
    const bool act = (q < V4) && ((int)s_cmax16[q >> 2] >= c16);
    unsigned int ks[4];
    bool pr[4] = {false, false, false, false};
    const int j0 = q * 4;
    if (act) {
      float4 x4 = lg4[q];
      float raw[4] = {x4.x, x4.y, x4.z, x4.w};
      const int sh = j0 & 31;
      unsigned long long ww = (unsigned long long)s_seen[j0 >> 5] |
                              ((unsigned long long)s_seen[(j0 + 3) >> 5] << 32);
#pragma unroll
      for (int e = 0; e < 4; ++e) {
        float x = xform(raw[e], (ww >> (sh + e)) & 1ull, rp, irp, itemp);
        ks[e] = fkey(x);
        pr[e] = (ks[e] >= fk0);
      }
    }
    int cnt = (int)pr[0] + (int)pr[1] + (int)pr[2] + (int)pr[3];
    int inc = cnt;
#pragma unroll
    for (int d = 1; d < 64; d <<= 1) {
      int t = __shfl_up(inc, d);
      if (lane >= d) inc += t;
    }
    const int total = __shfl(inc, 63);
    if (total) {
      int basep = 0;
      if (lane == 0) basep = atomicAdd(&s_cnt, total);
      basep = __shfl(basep, 0);
      int off = basep + inc - cnt;
#pragma unroll
      for (int e = 0; e < 4; ++e) {
        if (pr[e]) {
          if (off < CAP)
            s_key[off] = ((unsigned long long)ks[e] << 32) | (unsigned int)(j0 + e);
          ++off;
        }
      }
    }
  }
  __syncthreads();
  int G = s_cnt;
  if (G > CAP) G = CAP;
  const int kk = k > G ? G : k;

  // ---- 1-pass radix: bucket (fkey>>20) of the kk-th largest candidate ----
  for (int i = tid; i < HSZ; i += 1024) s_hist[i] = 0;
  __syncthreads();
  for (int i = tid; i < G; i += 1024)
    atomicAdd(&s_hist[HIDX((unsigned int)(s_key[i] >> 52))], 1);
  __syncthreads();
  if (wid == 0) {
    wave_suffix_select_p(s_hist, kk, lane, &s_selb, &s_selrem);
    if (lane == 0) s_scnt = 0;
  }
  __syncthreads();
  const unsigned int b1 = (unsigned int)s_selb;

  // ---- compact survivor-superset (top12 >= b1) into s_key2 ----
  for (int ib = 0; ib < G; ib += 1024) {
    const int i = ib + tid;
    const bool p = (i < G) && ((unsigned int)(s_key[i] >> 52) >= b1);
    unsigned long long mask = __ballot(p);
    if (!mask) continue;
    int basep = 0;
    if (lane == 0) basep = atomicAdd(&s_scnt, __popcll(mask));
    basep = __shfl(basep, 0);
    if (p) {
      int pos = basep + __popcll(mask & ((1ull << lane) - 1ull));
      if (pos < CAPS) s_key2[pos] = s_key[i];
    }
  }
  __syncthreads();
  int S = s_scnt;
  if (S > CAPS) S = CAPS;
  const float m = s_mv;

  // ---- counting sort by value bins (exact), fallback bitonic if dense bin ----
  const unsigned int cbase = b1 << 20;
  const unsigned int span = fkey(m) - cbase;
  int shiftb;
  {
    int bits = 32 - __clz((int)(span | 1u));
    shiftb = bits > 12 ? bits - 12 : 0;
  }
  for (int i = tid; i < HSZ; i += 1024) s_hist[i] = 0;
  __syncthreads();
  for (int i = tid; i < S; i += 1024) {
    unsigned int hi = (unsigned int)(s_key2[i] >> 32);
    int b = (int)((hi - cbase) >> shiftb);
    if (b > 4095) b = 4095;
    atomicAdd(&s_hist[HIDX(b)], 1);
  }
  __syncthreads();
  if (wid == 0) {
    int T = 0, mx = 0;
    const int bb = lane * 64;
    for (int i = 0; i < 64; ++i) {
      int c = s_hist[HIDX(bb + i)];
      T += c;
      mx = c > mx ? c : mx;
    }
    int ex = T;
#pragma unroll
    for (int d = 1; d < 64; d <<= 1) {
      int t = __shfl_up(ex, d);
      if (lane >= d) ex += t;
    }
    ex -= T;  // exclusive offset for this lane's 64 bins
    int run = ex;
    for (int i = 0; i < 64; ++i) {
      int idx = HIDX(bb + i);
      int c = s_hist[idx];
      s_hist[idx] = run;
      run += c;
    }
#pragma unroll
    for (int d = 32; d > 0; d >>= 1) {
      int o = __shfl_xor(mx, d);
      mx = o > mx ? o : mx;
    }
    if (lane == 0) s_maxpop = mx;
  }
  __syncthreads();

  if (s_maxpop <= 16) {
    // scatter by bin (arbitrary within-bin order)
    for (int i = tid; i < S; i += 1024) {
      unsigned long long key = s_key2[i];
      unsigned int hi = (unsigned int)(key >> 32);
      int b = (int)((hi - cbase) >> shiftb);
      if (b > 4095) b = 4095;
      int pos = atomicAdd(&s_hist[HIDX(b)], 1);
      s_skey[pos] = key;
    }
    __syncthreads();
    // per-bin exact insertion sort (disjoint segments per thread)
    for (int b = tid; b < 4096; b += 1024) {
      int endb = s_hist[HIDX(b)];
      int st = (b == 0) ? 0 : s_hist[HIDX(b - 1)];
      for (int i = st + 1; i < endb; ++i) {
        unsigned long long key = s_skey[i];
        int j = i - 1;
        while (j >= st && s_skey[j] > key) {
          s_skey[j + 1] = s_skey[j];
          --j;
        }
        s_skey[j + 1] = key;
      }
    }
    __syncthreads();
  } else {
    // bitonic fallback on s_key2, copy to s_skey
    int np2 = 2;
    while (np2 < S) np2 <<= 1;
    for (int i = S + tid; i < np2; i += 1024) s_key2[i] = ~0ull;
    __syncthreads();
    for (int size = 2; size <= np2; size <<= 1) {
      for (int stride = size >> 1; stride > 0; stride >>= 1) {
        for (int t2 = tid; t2 < (np2 >> 1); t2 += 1024) {
          int pos = 2 * t2 - (t2 & (stride - 1));
          int qq = pos + stride;
          bool up = ((pos & size) == 0);
          unsigned long long a = s_key2[pos], b = s_key2[qq];
          if ((a > b) == up) { s_key2[pos] = b; s_key2[qq] = a; }
        }
        __syncthreads();
      }
    }
    for (int i = tid; i < S; i += 1024) s_skey[i] = s_key2[i];
    __syncthreads();
  }

  // ---- exact kth + survivor range [p0, S) ----
  const unsigned int kthkey32 = (unsigned int)(s_skey[S - kk] >> 32);
  for (int i = tid; i < S; i += 1024) {
    unsigned int hi = (unsigned int)(s_skey[i] >> 32);
    if (hi >= kthkey32 && (i == 0 || (unsigned int)(s_skey[i - 1] >> 32) < kthkey32))
      s_p0v = i;
  }
  __syncthreads();
  const int p0 = s_p0v;
  const int L = S - p0;   // true survivors (>= kth value), shifted arrays [0,L)

  // ---- softmax denom over survivors ----
  float part = 0.0f;
  for (int i = tid; i < L; i += 1024) {
    float x = ikey((unsigned int)(s_skey[p0 + i] >> 32));
    float e = expf(x - m);
    s_e2[i] = e;
    part += e;
  }
#pragma unroll
  for (int d = 32; d > 0; d >>= 1) part += __shfl_xor(part, d);
  if (lane == 0) s_wredf[wid] = part;
  __syncthreads();
  if (tid == 0) {
    float s = 0.0f;
    for (int i = 0; i < 16; ++i) s += s_wredf[i];
    s_dn1 = s;
  }
  __syncthreads();
  const float denom = s_dn1;

  for (int i = tid; i < L; i += 1024) s_q2[i] = s_e2[i] / denom;
  __syncthreads();

  // ---- serial fp32 cumsum (pure add chain) + top-p mask, last kept ----
  if (tid == 0) {
    const float cut = 1.0f - topp;
    float cs = 0.0f;
    int i = 0;
    for (; i + 16 <= L; i += 16) {
      vfloat4 a = *(const vfloat4*)&s_q2[i];
      vfloat4 b = *(const vfloat4*)&s_q2[i + 4];
      vfloat4 c = *(const vfloat4*)&s_q2[i + 8];
      vfloat4 d = *(const vfloat4*)&s_q2[i + 12];
      unsigned int w0, w1, w2, w3;
      cs += a.x; w0  = (cs <= cut) ? 0u : 1u;
      cs += a.y; w0 |= ((cs <= cut) ? 0u : 1u) << 8;
      cs += a.z; w0 |= ((cs <= cut) ? 0u : 1u) << 16;
      cs += a.w; w0 |= ((cs <= cut) ? 0u : 1u) << 24;
      cs += b.x; w1  = (cs <= cut) ? 0u : 1u;
      cs += b.y; w1 |= ((cs <= cut) ? 0u : 1u) << 8;
      cs += b.z; w1 |= ((cs <= cut) ? 0u : 1u) << 16;
      cs += b.w; w1 |= ((cs <= cut) ? 0u : 1u) << 24;
      cs += c.x; w2  = (cs <= cut) ? 0u : 1u;
      cs += c.y; w2 |= ((cs <= cut) ? 0u : 1u) << 8;
      cs += c.z; w2 |= ((cs <= cut) ? 0u : 1u) << 16;
      cs += c.w; w2 |= ((cs <= cut) ? 0u : 1u) << 24;
      cs += d.x; w3  = (cs <= cut) ? 0u : 1u;
      cs += d.y; w3 |= ((cs <= cut) ? 0u : 1u) << 8;
      cs += d.z; w3 |= ((cs <= cut) ? 0u : 1u) << 16;
      cs += d.w; w3 |= ((cs <= cut) ? 0u : 1u) << 24;
      *(unsigned int*)&s_keep[i] = w0;
      *(unsigned int*)&s_keep[i + 4] = w1;
      *(unsigned int*)&s_keep[i + 8] = w2;
      *(unsigned int*)&s_keep[i + 12] = w3;
    }
    for (; i < L; ++i) {
      cs += s_q2[i];
      s_keep[i] = (cs <= cut) ? 0 : 1;
    }
    s_keep[L - 1] = 1;
  }
  __syncthreads();

  // ---- final denom over kept ----
  part = 0.0f;
  for (int i = tid; i < L; i += 1024)
    if (s_keep[i]) part += s_e2[i];
#pragma unroll
  for (int d = 32; d > 0; d >>= 1) part += __shfl_xor(part, d);
  if (lane == 0) s_wredf[wid] = part;
  __syncthreads();
  if (tid == 0) {
    float s = 0.0f;
    for (int i = 0; i < 16; ++i) s += s_wredf[i];
    s_dn2 = s;
  }
  __syncthreads();
  const float denom2 = s_dn2;

  for (int i = tid; i < L; i += 1024)
    s_e2[i] = s_keep[i] ? (s_e2[i] / denom2) : 0.0f;
  __syncthreads();

  // ---- Gumbel argmax over kept survivors ----
  float bs = -INFINITY;
  int bi = 0x7FFFFFFF;
  for (int i = tid; i < L; i += 1024) {
    if (!s_keep[i]) continue;
    unsigned long long kv = s_skey[p0 + i];
    int j = (int)(kv & 0xFFFFFFFFull);
    float x = ikey((unsigned int)(kv >> 32));
    unsigned int t = (unsigned int)(row * V) + (unsigned int)j;
    unsigned int bb = tf_bits(t);
    float u = __uint_as_float((bb >> 9) | 0x3f800000u) - 1.0f;
    if (u < TINYF) u = TINYF;
    float g = -logf(-logf(u));
    float sc = x + g;
    if (sc > bs || (sc == bs && j < bi)) { bs = sc; bi = j; }
  }

  // ---- scatter nonzero probs (zeros laid down by kAZ) ----
  for (int i = tid; i < L; i += 1024) {
    int j = (int)(s_skey[p0 + i] & 0xFFFFFFFFull);
    prow[j] = s_e2[i];
  }

  // ---- argmax reduce -> sampled id ----
#pragma unroll
  for (int d = 32; d > 0; d >>= 1) {
    float ov = __shfl_down(bs, d);
    int oi = __shfl_down(bi, d);
    if (ov > bs || (ov == bs && oi < bi)) { bs = ov; bi = oi; }
  }
  if (lane == 0) { s_wredf[wid] = bs; s_wredi[wid] = bi; }
  __syncthreads();
  if (tid == 0) {
    float bb = s_wredf[0];
    int bj = s_wredi[0];
    for (int i = 1; i < 16; ++i) {
      if (s_wredf[i] > bb || (s_wredf[i] == bb && s_wredi[i] < bj)) {
        bb = s_wredf[i];
        bj = s_wredi[i];
      }
    }
    out_ids[row] = (float)bj;
  }
}

// ================== Fallback: monolithic kernel (ws too small) ==================
__global__ __launch_bounds__(1024, 1) void sampler_mono(
    const float* __restrict__ logits, const int* __restrict__ toks,
    const float* __restrict__ temps, const float* __restrict__ topps,
    const int* __restrict__ topks, const float* __restrict__ rps,
    float* __restrict__ out_ids, float* __restrict__ probs) {
  __shared__ unsigned int s_seen[VW];
  __shared__ int s_hist[4096];
  __shared__ unsigned short s_cmax16[NCHUNK];
  __shared__ float s_sval[CAPM];
  __shared__ int s_sidx[CAPM];
  __shared__ float s_e[CAPM];
  __shared__ unsigned char s_keep[CAPM];
  __shared__ float s_wredf[16];
  __shared__ int s_wredi[16];
  __shared__ float s_m, s_denom, s_denom2;
  __shared__ int s_b0, s_cnt, s_p0;

  const int row = blockIdx.x;
  const int tid = threadIdx.x;
  const int lane = tid & 63;
  const int wid = tid >> 6;
  const float rp = rps[row];
  const float irp = 1.0f / rp;
  const float itemp = 1.0f / temps[row];
  const float topp = topps[row];
  const int k = topks[row];
  const size_t base = (size_t)row * V;
  const float4* __restrict__ lg4 = reinterpret_cast<const float4*>(logits + base);
  vfloat4* __restrict__ pr4 = reinterpret_cast<vfloat4*>(probs + base);

  for (int i = tid; i < VW; i += 1024) s_seen[i] = 0u;
  for (int i = tid; i < 4096; i += 1024) s_hist[i] = 0;
  __syncthreads();
  for (int i = tid; i < W; i += 1024) {
    int tok = toks[row * W + i];
    if (tok >= 0 && tok < V) atomicOr(&s_seen[tok >> 5], 1u << (tok & 31));
  }
  __syncthreads();

  float lmax = -INFINITY;
  for (int qb = 0; qb < V4; qb += 1024) {
    const int q = qb + tid;
    unsigned int kmax = 0u;
    if (q < V4) {
      float4 x4 = lg4[q];
      float xs[4] = {x4.x, x4.y, x4.z, x4.w};
      const int j0 = q * 4;
      const int sh = j0 & 31;
      unsigned long long ww = (unsigned long long)s_seen[j0 >> 5] |
                              ((unsigned long long)s_seen[(j0 + 3) >> 5] << 32);
#pragma unroll
      for (int e = 0; e < 4; ++e) {
        float x = xform(xs[e], (ww >> (sh + e)) & 1ull, rp, irp, itemp);
        lmax = fmaxf(lmax, x);
        unsigned int ky = fkey(x);
        kmax = kmax > ky ? kmax : ky;
      }
    }
    unsigned int o;
    o = __shfl_xor(kmax, 1); kmax = kmax > o ? kmax : o;
    o = __shfl_xor(kmax, 2); kmax = kmax > o ? kmax : o;
    if (((lane & 3) == 0) && (q < V4)) s_cmax16[q >> 2] = (unsigned short)(kmax >> 16);
  }
#pragma unroll
  for (int d = 32; d > 0; d >>= 1) lmax = fmaxf(lmax, __shfl_xor(lmax, d));
  if (lane == 0) s_wredf[wid] = lmax;
  __syncthreads();
  for (int i = tid; i < NCHUNK; i += 1024)
    atomicAdd(&s_hist[s_cmax16[i] >> 4], 1);
  __syncthreads();
  if (wid == 1 && lane == 0) {
    float mm = s_wredf[0];
    for (int i = 1; i < 16; ++i) mm = fmaxf(mm, s_wredf[i]);
    s_m = mm;
  }
  if (wid == 0) {
    int sm = 0;
    const int bb = lane * 64;
    for (int i = 0; i < 64; ++i) sm += s_hist[bb + i];
    int sfx = sm;
#pragma unroll
    for (int d = 1; d < 64; d <<= 1) {
      int t = __shfl_down(sfx, d);
      if (lane + d < 64) sfx += t;
    }
    unsigned long long mk = __ballot(sfx >= k);
    const int cstar = 63 - __builtin_clzll(mk);
    const int above = __shfl(sfx, cstar) - __shfl(sm, cstar);
    int h = s_hist[cstar * 64 + lane];
    int sfx2 = h;
#pragma unroll
    for (int d = 1; d < 64; d <<= 1) {
      int t = __shfl_down(sfx2, d);
      if (lane + d < 64) sfx2 += t;
    }
    unsigned long long mk2 = __ballot(above + sfx2 >= k);
    const int boff = 63 - __builtin_clzll(mk2);
    if (lane == 0) { s_b0 = cstar * 64 + boff; s_cnt = 0; }
  }
  __syncthreads();
  const int b0 = s_b0;
  const unsigned int fk0 = ((unsigned int)b0) << 20;
  const int c16 = b0 << 4;
  for (int qb = 0; qb < V4; qb += 1024) {
    const int q = qb + tid;
    const bool act = (q < V4) && ((int)s_cmax16[q >> 2] >= c16);
    float xs[4];
    bool pr[4] = {false, false, false, false};
    const int j0 = q * 4;
    if (act) {
      float4 x4 = lg4[q];
      float raw[4] = {x4.x, x4.y, x4.z, x4.w};
      const int sh = j0 & 31;
      unsigned long long ww = (unsigned long long)s_seen[j0 >> 5] |
                              ((unsigned long long)s_seen[(j0 + 3) >> 5] << 32);
#pragma unroll
      for (int e = 0; e < 4; ++e) {
        xs[e] = xform(raw[e], (ww >> (sh + e)) & 1ull, rp, irp, itemp);
        pr[e] = (fkey(xs[e]) >= fk0);
      }
    }
#pragma unroll
    for (int e = 0; e < 4; ++e) {
      unsigned long long mask = __ballot(pr[e]);
      if (!mask) continue;
      int basep = 0;
      if (lane == 0) basep = atomicAdd(&s_cnt, __popcll(mask));
      basep = __shfl(basep, 0);
      if (pr[e]) {
        int pos = basep + __popcll(mask & ((1ull << lane) - 1ull));
        if (pos < CAPM) { s_sval[pos] = xs[e]; s_sidx[pos] = j0 + e; }
      }
    }
  }
  __syncthreads();
  int G = s_cnt;
  if (G > CAPM) G = CAPM;
  int np2 = 2;
  while (np2 < G) np2 <<= 1;
  for (int i = G + tid; i < np2; i += 1024) {
    s_sval[i] = INFINITY;
    s_sidx[i] = 0x7FFFFFFF;
  }
  __syncthreads();
  for (int size = 2; size <= np2; size <<= 1) {
    for (int stride = size >> 1; stride > 0; stride >>= 1) {
      for (int t2 = tid; t2 < (np2 >> 1); t2 += 1024) {
        int pos = 2 * t2 - (t2 & (stride - 1));
        int qq = pos + stride;
        bool up = ((pos & size) == 0);
        float v1 = s_sval[pos], v2 = s_sval[qq];
        int i1 = s_sidx[pos], i2 = s_sidx[qq];
        bool gt = (v1 > v2) || (v1 == v2 && i1 > i2);
        if (gt == up) {
          s_sval[pos] = v2; s_sval[qq] = v1;
          s_sidx[pos] = i2; s_sidx[qq] = i1;
        }
      }
      __syncthreads();
    }
  }
  const int kk = k > G ? G : k;
  const float kth = s_sval[G - kk];
  const float m = s_m;
  for (int i = tid; i < G; i += 1024) {
    if (s_sval[i] >= kth && (i == 0 || s_sval[i - 1] < kth)) s_p0 = i;
  }
  __syncthreads();
  const int p0 = s_p0;
  float part = 0.0f;
  for (int i = p0 + tid; i < G; i += 1024) {
    float e = expf(s_sval[i] - m);
    s_e[i] = e;
    part += e;
  }
#pragma unroll
  for (int d = 32; d > 0; d >>= 1) part += __shfl_xor(part, d);
  if (lane == 0) s_wredf[wid] = part;
  __syncthreads();
  if (tid == 0) {
    float s = 0.0f;
    for (int i = 0; i < 16; ++i) s += s_wredf[i];
    s_denom = s;
  }
  __syncthreads();
  const float denom = s_denom;
  if (tid == 0) {
    const float cut = 1.0f - topp;
    float cs = 0.0f;
    for (int i = p0; i < G; ++i) {
      cs += s_e[i] / denom;
      s_keep[i] = (cs <= cut) ? 0 : 1;
    }
    s_keep[G - 1] = 1;
  }
  __syncthreads();
  part = 0.0f;
  for (int i = p0 + tid; i < G; i += 1024)
    if (s_keep[i]) part += s_e[i];
#pragma unroll
  for (int d = 32; d > 0; d >>= 1) part += __shfl_xor(part, d);
  if (lane == 0) s_wredf[wid] = part;
  __syncthreads();
  if (tid == 0) {
    float s = 0.0f;
    for (int i = 0; i < 16; ++i) s += s_wredf[i];
    s_denom2 = s;
  }
  __syncthreads();
  const float denom2 = s_denom2;
  for (int i = p0 + tid; i < G; i += 1024)
    s_e[i] = s_keep[i] ? (s_e[i] / denom2) : 0.0f;
  __syncthreads();
  float bs = -INFINITY;
  int bi = 0x7FFFFFFF;
  for (int i = p0 + tid; i < G; i += 1024) {
    if (!s_keep[i]) continue;
    int j = s_sidx[i];
    unsigned int t = (unsigned int)(row * V) + (unsigned int)j;
    unsigned int bb = tf_bits(t);
    float u = __uint_as_float((bb >> 9) | 0x3f800000u) - 1.0f;
    if (u < TINYF) u = TINYF;
    float g = -logf(-logf(u));
    float sc = s_sval[i] + g;
    if (sc > bs || (sc == bs && j < bi)) { bs = sc; bi = j; }
  }
  const unsigned int kkey = fkey(kth);
  const int k16 = (int)(kkey >> 16);
  for (int q = tid; q < V4; q += 1024) {
    vfloat4 o = (vfloat4){0.0f, 0.0f, 0.0f, 0.0f};
    if ((int)s_cmax16[q >> 2] >= k16) {
      float4 x4 = lg4[q];
      float raw[4] = {x4.x, x4.y, x4.z, x4.w};
      float os[4];
      const int j0 = q * 4;
      const int sh = j0 & 31;
      unsigned long long ww = (unsigned long long)s_seen[j0 >> 5] |
                              ((unsigned long long)s_seen[(j0 + 3) >> 5] << 32);
#pragma unroll
      for (int e = 0; e < 4; ++e) {
        float x = xform(raw[e], (ww >> (sh + e)) & 1ull, rp, irp, itemp);
        float pr = 0.0f;
        if (x >= kth) {
          int j = j0 + e;
          int lo = p0, hi = G;
          while (lo < hi) {
            int mid = (lo + hi) >> 1;
            float v = s_sval[mid];
            int id = s_sidx[mid];
            if (v < x || (v == x && id < j)) lo = mid + 1; else hi = mid;
          }
          pr = s_e[lo];
        }
        os[e] = pr;
      }
      o.x = os[0]; o.y = os[1]; o.z = os[2]; o.w = os[3];
    }
    pr4[q] = o;
  }
#pragma unroll
  for (int d = 32; d > 0; d >>= 1) {
    float ov = __shfl_down(bs, d);
    int oi = __shfl_down(bi, d);
    if (ov > bs || (ov == bs && oi < bi)) { bs = ov; bi = oi; }
  }
  if (lane == 0) { s_wredf[wid] = bs; s_wredi[wid] = bi; }
  __syncthreads();
  if (tid == 0) {
    float bb = s_wredf[0];
    int bj = s_wredi[0];
    for (int i = 1; i < 16; ++i) {
      if (s_wredf[i] > bb || (s_wredf[i] == bb && s_wredi[i] < bj)) {
        bb = s_wredf[i];
        bj = s_wredi[i];
      }
    }
    out_ids[row] = (float)bj;
  }
}

extern "C" void kernel_launch(void* const* d_in, const int* in_sizes, int n_in,
                              void* d_out, int out_size, void* d_ws, size_t ws_size,
                              hipStream_t stream) {
  (void)in_sizes; (void)out_size;
  if (n_in < 6) return;
  const float* logits = (const float*)d_in[0];
  const int* toks = (const int*)d_in[1];
  const float* temps = (const float*)d_in[2];
  const float* topps = (const float*)d_in[3];
  const int* topks = (const int*)d_in[4];
  const float* rps = (const float*)d_in[5];
  float* out = (float*)d_out;            // [0,256): ids as float; [256,...): probs
  float* probs = out + NROWS;

  if (ws_size >= WS_NEED && d_ws != nullptr) {
    char* w = (char*)d_ws;
    unsigned short* ws_cmax = (unsigned short*)(w + WS_CMAX);
    float* ws_bmax = (float*)(w + WS_BMAX);
    kAZ_chunkmax<<<dim3(NROWS * NSLICE), dim3(256), 0, stream>>>(
        logits, toks, temps, rps, ws_cmax, ws_bmax, probs);
    kB_select<<<dim3(NROWS), dim3(1024), 0, stream>>>(
        logits, toks, temps, topps, topks, rps, ws_cmax, ws_bmax, out, probs);
  } else {
    sampler_mono<<<dim3(NROWS), dim3(1024), 0, stream>>>(
        logits, toks, temps, topps, topks, rps, out, probs);
  }
}

// Round 10
// 100.562 us; speedup vs baseline: 2.4795x; 1.1919x over previous
//
#include <hip/hip_runtime.h>

#define V 128000
#define V4 (V / 4)
#define NCHUNK (V / 16)      // 8000 chunk-max entries (16 elems each)
#define NROWS 256
#define NSLICE 8
#define SL4 (V4 / NSLICE)    // 4000 float4 per slice
#define W 200
#define VW (V / 32)          // 4000 words of seen-bitmask
#define CAP 4096             // candidate capacity
#define CAPS 2048            // survivor capacity
#define CAPM 8192            // mono-kernel capacity
#define TINYF 1.17549435e-38f
#define HIDX(b) ((b) + ((b) >> 5))   // padded hist index (4096 -> 4224 slots)
#define HSZ 4224

// ---- d_ws layout ----
#define WS_CMAX   0u          // u16[256][8000]
#define WS_BMAX   4104192u    // float[256][8]
#define WS_NEED   16777216u

typedef float vfloat4 __attribute__((ext_vector_type(4)));

// LDS-only barrier: drain LDS ops, sync waves, but let global STORES float
// across (they are drained by the one full __syncthreads before the scatter).
__device__ __forceinline__ void bar_lds() {
  asm volatile("s_waitcnt lgkmcnt(0)" ::: "memory");
  __builtin_amdgcn_s_barrier();
}

__device__ __forceinline__ unsigned int fkey(float x) {
  unsigned int u = __float_as_uint(x);
  return (u & 0x80000000u) ? ~u : (u | 0x80000000u);
}
__device__ __forceinline__ float ikey(unsigned int k) {
  unsigned int u = (k & 0x80000000u) ? (k & 0x7FFFFFFFu) : ~k;
  return __uint_as_float(u);
}

// ---- jax threefry2x32, partitionable: counter=(0,t), key=(0,42), fold=xor ----
__device__ __forceinline__ unsigned int tf_bits(unsigned int t) {
  const unsigned int k0 = 0u, k1 = 42u;
  const unsigned int ks2 = k0 ^ k1 ^ 0x1BD11BDAu;
  unsigned int x0 = 0u + k0, x1 = t + k1;
  const unsigned int ksArr[3] = {k0, k1, ks2};
  const int RA[4] = {13, 15, 26, 6};
  const int RB[4] = {17, 29, 16, 24};
#pragma unroll
  for (int i = 0; i < 5; ++i) {
#pragma unroll
    for (int j = 0; j < 4; ++j) {
      int r = (i & 1) ? RB[j] : RA[j];
      x0 += x1;
      x1 = (x1 << r) | (x1 >> (32 - r));
      x1 ^= x0;
    }
    x0 += ksArr[(i + 1) % 3];
    x1 += ksArr[(i + 2) % 3] + (unsigned int)(i + 1);
  }
  return x0 ^ x1;
}

__device__ __forceinline__ float xform(float x, bool seen, float rp, float irp,
                                        float itemp) {
  if (seen) x = (x > 0.0f) ? x * irp : x * rp;
  return x * itemp;
}

// Wave-parallel suffix select over a padded 4096-bucket histogram (one wave).
__device__ __forceinline__ void wave_suffix_select_p(const int* hist, int need,
                                                     int lane, int* out_b,
                                                     int* out_rem) {
  int sm = 0;
  const int bb = lane * 64;
  for (int i = 0; i < 64; ++i) sm += hist[HIDX(bb + i)];
  int sfx = sm;
#pragma unroll
  for (int d = 1; d < 64; d <<= 1) {
    int t = __shfl_down(sfx, d);
    if (lane + d < 64) sfx += t;
  }
  unsigned long long mk = __ballot(sfx >= need);
  const int cstar = 63 - __builtin_clzll(mk);
  const int aboveC = __shfl(sfx, cstar) - __shfl(sm, cstar);
  int h = hist[HIDX(cstar * 64 + lane)];
  int sfx2 = h;
#pragma unroll
  for (int d = 1; d < 64; d <<= 1) {
    int t = __shfl_down(sfx2, d);
    if (lane + d < 64) sfx2 += t;
  }
  unsigned long long mk2 = __ballot(aboveC + sfx2 >= need);
  const int boff = 63 - __builtin_clzll(mk2);
  const int aboveB = aboveC + __shfl(sfx2, boff) - __shfl(h, boff);
  if (lane == 0) {
    *out_b = cstar * 64 + boff;
    *out_rem = need - aboveB;
  }
}

// ====== Kernel A: transform + chunk-max + slice-max (pure read) ======
__global__ __launch_bounds__(256) void kA_chunkmax(
    const float* __restrict__ logits, const int* __restrict__ toks,
    const float* __restrict__ temps, const float* __restrict__ rps,
    unsigned short* __restrict__ ws_cmax, float* __restrict__ ws_bmax) {
  __shared__ unsigned int s_seen[VW];
  __shared__ float s_red[4];
  const int row = blockIdx.x >> 3;
  const int slice = blockIdx.x & 7;
  const int tid = threadIdx.x;
  const int lane = tid & 63;
  const int wid = tid >> 6;
  const float rp = rps[row];
  const float irp = 1.0f / rp;
  const float itemp = 1.0f / temps[row];
  const size_t base = (size_t)row * V;
  const float4* __restrict__ lg4 = reinterpret_cast<const float4*>(logits + base);

  for (int i = tid; i < VW; i += 256) s_seen[i] = 0u;
  __syncthreads();
  for (int i = tid; i < W; i += 256) {
    int tok = toks[row * W + i];
    if (tok >= 0 && tok < V) atomicOr(&s_seen[tok >> 5], 1u << (tok & 31));
  }
  __syncthreads();

  float lmax = -INFINITY;
  const int q0 = slice * SL4;
  for (int qi = tid; qi < SL4; qi += 256) {
    const int q = q0 + qi;
    float4 x4 = lg4[q];
    float xs[4] = {x4.x, x4.y, x4.z, x4.w};
    const int j0 = q * 4;
    const int sh = j0 & 31;
    unsigned long long ww = (unsigned long long)s_seen[j0 >> 5] |
                            ((unsigned long long)s_seen[(j0 + 3) >> 5] << 32);
    unsigned int kmax = 0u;
#pragma unroll
    for (int e = 0; e < 4; ++e) {
      float x = xform(xs[e], (ww >> (sh + e)) & 1ull, rp, irp, itemp);
      lmax = fmaxf(lmax, x);
      unsigned int ky = fkey(x);
      kmax = kmax > ky ? kmax : ky;
    }
    unsigned int o;
    o = __shfl_xor(kmax, 1); kmax = kmax > o ? kmax : o;
    o = __shfl_xor(kmax, 2); kmax = kmax > o ? kmax : o;
    if ((lane & 3) == 0) ws_cmax[row * NCHUNK + (q >> 2)] = (unsigned short)(kmax >> 16);
  }
#pragma unroll
  for (int d = 32; d > 0; d >>= 1) lmax = fmaxf(lmax, __shfl_xor(lmax, d));
  if (lane == 0) s_red[wid] = lmax;
  __syncthreads();
  if (tid == 0) {
    float mm = fmaxf(fmaxf(s_red[0], s_red[1]), fmaxf(s_red[2], s_red[3]));
    ws_bmax[row * NSLICE + slice] = mm;
  }
}

// ====== Kernel B: zero-fill (riding gather) + select + sort + top-p + sample ======
__global__ __launch_bounds__(1024) void kB_select(
    const float* __restrict__ logits, const int* __restrict__ toks,
    const float* __restrict__ temps, const float* __restrict__ topps,
    const int* __restrict__ topks, const float* __restrict__ rps,
    const unsigned short* __restrict__ ws_cmax, const float* __restrict__ ws_bmax,
    float* __restrict__ out_ids, float* __restrict__ probs) {
  __shared__ unsigned long long s_key[CAP];             // 32 KB; chunk-hist / candidates / sorted
  __shared__ __align__(16) unsigned char s_bufA[HSZ*4]; // 16.9 KB; seen -> radix/count hist
  __shared__ __align__(16) unsigned char s_bufB[16384]; // 16 KB; cmax16 -> survivors
  __shared__ __align__(16) float s_e2[CAPS];            // 8 KB survivor exp / final probs
  __shared__ __align__(16) float s_q2[CAPS];            // 8 KB survivor p = e/denom
  __shared__ unsigned char s_keep[CAPS];                // 2 KB
  __shared__ float s_wredf[16];
  __shared__ int s_wredi[16];
  __shared__ float s_mv, s_dn1, s_dn2;
  __shared__ int s_b0, s_cnt, s_scnt, s_selb, s_selrem, s_p0v, s_maxpop;

  int* s_hist0 = (int*)s_key;                 // padded chunk hist (dead before keys)
  unsigned int* s_seen = (unsigned int*)s_bufA;
  int* s_hist = (int*)s_bufA;                 // padded radix/counting hist
  unsigned short* s_cmax16 = (unsigned short*)s_bufB;
  unsigned long long* s_key2 = (unsigned long long*)s_bufB;  // survivors (unsorted)
  unsigned long long* s_skey = s_key;         // sorted survivors (candidates dead)

  const int row = blockIdx.x;
  const int tid = threadIdx.x;
  const int lane = tid & 63;
  const int wid = tid >> 6;
  const float rp = rps[row];
  const float irp = 1.0f / rp;
  const float itemp = 1.0f / temps[row];
  const float topp = topps[row];
  const int k = topks[row];
  const size_t base = (size_t)row * V;
  const float4* __restrict__ lg4 = reinterpret_cast<const float4*>(logits + base);
  float* __restrict__ prow = probs + base;
  vfloat4* __restrict__ pr4 = reinterpret_cast<vfloat4*>(prow);

  // init: seen=0, chunk-hist=0, cmax->LDS
  for (int i = tid; i < VW; i += 1024) s_seen[i] = 0u;
  for (int i = tid; i < HSZ; i += 1024) s_hist0[i] = 0;
  {
    const unsigned int* cm32 = reinterpret_cast<const unsigned int*>(ws_cmax + row * NCHUNK);
    unsigned int* sc32 = reinterpret_cast<unsigned int*>(s_cmax16);
    for (int i = tid; i < NCHUNK / 2; i += 1024) sc32[i] = cm32[i];
  }
  __syncthreads();
  for (int i = tid; i < W; i += 1024) {
    int tok = toks[row * W + i];
    if (tok >= 0 && tok < V) atomicOr(&s_seen[tok >> 5], 1u << (tok & 31));
  }
  for (int i = tid; i < NCHUNK; i += 1024)
    atomicAdd(&s_hist0[HIDX(s_cmax16[i] >> 4)], 1);
  __syncthreads();

  // bucket select b0 (wave 0); row max m (wave 1)
  if (wid == 1 && lane == 0) {
    float mm = ws_bmax[row * NSLICE];
    for (int i = 1; i < NSLICE; ++i) mm = fmaxf(mm, ws_bmax[row * NSLICE + i]);
    s_mv = mm;
  }
  if (wid == 0) {
    wave_suffix_select_p(s_hist0, k, lane, &s_b0, &s_selrem);
    if (lane == 0) s_cnt = 0;
  }
  __syncthreads();
  const int b0 = s_b0;

  // gather candidates + ZERO-FILL probs (stores drain in background)
  const vfloat4 z4 = (vfloat4){0.0f, 0.0f, 0.0f, 0.0f};
  const unsigned int fk0 = ((unsigned int)b0) << 20;
  const int c16 = b0 << 4;
  for (int qb = 0; qb < V4; qb += 1024) {
    const int q = qb + tid;
    if (q < V4) pr4[q] = z4;                 // zero-fill rides the gather loop
    const bool act = (q < V4) && ((int)s_cmax16[q >> 2] >= c16);
    unsigned int ks[4];
    bool pr[4] = {false, false, false, false};
    const int j0 = q * 4;
    if (act) {
      float4 x4 = lg4[q];
      float raw[4] = {x4.x, x4.y, x4.z, x4.w};
      const int sh = j0 & 31;
      unsigned long long ww = (unsigned long long)s_seen[j0 >> 5] |
                              ((unsigned long long)s_seen[(j0 + 3) >> 5] << 32);
#pragma unroll
      for (int e = 0; e < 4; ++e) {
        float x = xform(raw[e], (ww >> (sh + e)) & 1ull, rp, irp, itemp);
        ks[e] = fkey(x);
        pr[e] = (ks[e] >= fk0);
      }
    }
    int cnt = (int)pr[0] + (int)pr[1] + (int)pr[2] + (int)pr[3];
    int inc = cnt;
#pragma unroll
    for (int d = 1; d < 64; d <<= 1) {
      int t = __shfl_up(inc, d);
      if (lane >= d) inc += t;
    }
    const int total = __shfl(inc, 63);
    if (total) {
      int basep = 0;
      if (lane == 0) basep = atomicAdd(&s_cnt, total);
      basep = __shfl(basep, 0);
      int off = basep + inc - cnt;
#pragma unroll
      for (int e = 0; e < 4; ++e) {
        if (pr[e]) {
          if (off < CAP)
            s_key[off] = ((unsigned long long)ks[e] << 32) | (unsigned int)(j0 + e);
          ++off;
        }
      }
    }
  }
  bar_lds();
  int G = s_cnt;
  if (G > CAP) G = CAP;
  const int kk = k > G ? G : k;

  // ---- 1-pass radix: bucket (fkey>>20) of the kk-th largest candidate ----
  for (int i = tid; i < HSZ; i += 1024) s_hist[i] = 0;
  bar_lds();
  for (int i = tid; i < G; i += 1024)
    atomicAdd(&s_hist[HIDX((unsigned int)(s_key[i] >> 52))], 1);
  bar_lds();
  if (wid == 0) {
    wave_suffix_select_p(s_hist, kk, lane, &s_selb, &s_selrem);
    if (lane == 0) s_scnt = 0;
  }
  bar_lds();
  const unsigned int b1 = (unsigned int)s_selb;

  // ---- compact survivor-superset (top12 >= b1) into s_key2 ----
  for (int ib = 0; ib < G; ib += 1024) {
    const int i = ib + tid;
    const bool p = (i < G) && ((unsigned int)(s_key[i] >> 52) >= b1);
    unsigned long long mask = __ballot(p);
    if (!mask) continue;
    int basep = 0;
    if (lane == 0) basep = atomicAdd(&s_scnt, __popcll(mask));
    basep = __shfl(basep, 0);
    if (p) {
      int pos = basep + __popcll(mask & ((1ull << lane) - 1ull));
      if (pos < CAPS) s_key2[pos] = s_key[i];
    }
  }
  bar_lds();
  int S = s_scnt;
  if (S > CAPS) S = CAPS;
  const float m = s_mv;

  // ---- counting sort by value bins (exact), fallback bitonic if dense bin ----
  const unsigned int cbase = b1 << 20;
  const unsigned int span = fkey(m) - cbase;
  int shiftb;
  {
    int bits = 32 - __clz((int)(span | 1u));
    shiftb = bits > 12 ? bits - 12 : 0;
  }
  for (int i = tid; i < HSZ; i += 1024) s_hist[i] = 0;
  bar_lds();
  for (int i = tid; i < S; i += 1024) {
    unsigned int hi = (unsigned int)(s_key2[i] >> 32);
    int b = (int)((hi - cbase) >> shiftb);
    if (b > 4095) b = 4095;
    atomicAdd(&s_hist[HIDX(b)], 1);
  }
  bar_lds();
  if (wid == 0) {
    int T = 0, mx = 0;
    const int bb = lane * 64;
    for (int i = 0; i < 64; ++i) {
      int c = s_hist[HIDX(bb + i)];
      T += c;
      mx = c > mx ? c : mx;
    }
    int ex = T;
#pragma unroll
    for (int d = 1; d < 64; d <<= 1) {
      int t = __shfl_up(ex, d);
      if (lane >= d) ex += t;
    }
    ex -= T;  // exclusive offset for this lane's 64 bins
    int run = ex;
    for (int i = 0; i < 64; ++i) {
      int idx = HIDX(bb + i);
      int c = s_hist[idx];
      s_hist[idx] = run;
      run += c;
    }
#pragma unroll
    for (int d = 32; d > 0; d >>= 1) {
      int o = __shfl_xor(mx, d);
      mx = o > mx ? o : mx;
    }
    if (lane == 0) s_maxpop = mx;
  }
  bar_lds();

  if (s_maxpop <= 16) {
    for (int i = tid; i < S; i += 1024) {
      unsigned long long key = s_key2[i];
      unsigned int hi = (unsigned int)(key >> 32);
      int b = (int)((hi - cbase) >> shiftb);
      if (b > 4095) b = 4095;
      int pos = atomicAdd(&s_hist[HIDX(b)], 1);
      s_skey[pos] = key;
    }
    bar_lds();
    for (int b = tid; b < 4096; b += 1024) {
      int endb = s_hist[HIDX(b)];
      int st = (b == 0) ? 0 : s_hist[HIDX(b - 1)];
      for (int i = st + 1; i < endb; ++i) {
        unsigned long long key = s_skey[i];
        int j = i - 1;
        while (j >= st && s_skey[j] > key) {
          s_skey[j + 1] = s_skey[j];
          --j;
        }
        s_skey[j + 1] = key;
      }
    }
    bar_lds();
  } else {
    int np2 = 2;
    while (np2 < S) np2 <<= 1;
    for (int i = S + tid; i < np2; i += 1024) s_key2[i] = ~0ull;
    bar_lds();
    for (int size = 2; size <= np2; size <<= 1) {
      for (int stride = size >> 1; stride > 0; stride >>= 1) {
        for (int t2 = tid; t2 < (np2 >> 1); t2 += 1024) {
          int pos = 2 * t2 - (t2 & (stride - 1));
          int qq = pos + stride;
          bool up = ((pos & size) == 0);
          unsigned long long a = s_key2[pos], b = s_key2[qq];
          if ((a > b) == up) { s_key2[pos] = b; s_key2[qq] = a; }
        }
        bar_lds();
      }
    }
    for (int i = tid; i < S; i += 1024) s_skey[i] = s_key2[i];
    bar_lds();
  }

  // ---- exact kth + survivor range [p0, S) ----
  const unsigned int kthkey32 = (unsigned int)(s_skey[S - kk] >> 32);
  for (int i = tid; i < S; i += 1024) {
    unsigned int hi = (unsigned int)(s_skey[i] >> 32);
    if (hi >= kthkey32 && (i == 0 || (unsigned int)(s_skey[i - 1] >> 32) < kthkey32))
      s_p0v = i;
  }
  bar_lds();
  const int p0 = s_p0v;
  const int L = S - p0;   // true survivors, shifted arrays [0,L)

  // ---- softmax denom over survivors ----
  float part = 0.0f;
  for (int i = tid; i < L; i += 1024) {
    float x = ikey((unsigned int)(s_skey[p0 + i] >> 32));
    float e = expf(x - m);
    s_e2[i] = e;
    part += e;
  }
#pragma unroll
  for (int d = 32; d > 0; d >>= 1) part += __shfl_xor(part, d);
  if (lane == 0) s_wredf[wid] = part;
  bar_lds();
  if (tid == 0) {
    float s = 0.0f;
    for (int i = 0; i < 16; ++i) s += s_wredf[i];
    s_dn1 = s;
  }
  bar_lds();
  const float denom = s_dn1;

  for (int i = tid; i < L; i += 1024) s_q2[i] = s_e2[i] / denom;
  bar_lds();

  // ---- serial fp32 cumsum (pure add chain) + top-p mask, last kept ----
  if (tid == 0) {
    const float cut = 1.0f - topp;
    float cs = 0.0f;
    int i = 0;
    for (; i + 16 <= L; i += 16) {
      vfloat4 a = *(const vfloat4*)&s_q2[i];
      vfloat4 b = *(const vfloat4*)&s_q2[i + 4];
      vfloat4 c = *(const vfloat4*)&s_q2[i + 8];
      vfloat4 d = *(const vfloat4*)&s_q2[i + 12];
      unsigned int w0, w1, w2, w3;
      cs += a.x; w0  = (cs <= cut) ? 0u : 1u;
      cs += a.y; w0 |= ((cs <= cut) ? 0u : 1u) << 8;
      cs += a.z; w0 |= ((cs <= cut) ? 0u : 1u) << 16;
      cs += a.w; w0 |= ((cs <= cut) ? 0u : 1u) << 24;
      cs += b.x; w1  = (cs <= cut) ? 0u : 1u;
      cs += b.y; w1 |= ((cs <= cut) ? 0u : 1u) << 8;
      cs += b.z; w1 |= ((cs <= cut) ? 0u : 1u) << 16;
      cs += b.w; w1 |= ((cs <= cut) ? 0u : 1u) << 24;
      cs += c.x; w2  = (cs <= cut) ? 0u : 1u;
      cs += c.y; w2 |= ((cs <= cut) ? 0u : 1u) << 8;
      cs += c.z; w2 |= ((cs <= cut) ? 0u : 1u) << 16;
      cs += c.w; w2 |= ((cs <= cut) ? 0u : 1u) << 24;
      cs += d.x; w3  = (cs <= cut) ? 0u : 1u;
      cs += d.y; w3 |= ((cs <= cut) ? 0u : 1u) << 8;
      cs += d.z; w3 |= ((cs <= cut) ? 0u : 1u) << 16;
      cs += d.w; w3 |= ((cs <= cut) ? 0u : 1u) << 24;
      *(unsigned int*)&s_keep[i] = w0;
      *(unsigned int*)&s_keep[i + 4] = w1;
      *(unsigned int*)&s_keep[i + 8] = w2;
      *(unsigned int*)&s_keep[i + 12] = w3;
    }
    for (; i < L; ++i) {
      cs += s_q2[i];
      s_keep[i] = (cs <= cut) ? 0 : 1;
    }
    s_keep[L - 1] = 1;
  }
  bar_lds();

  // ---- final denom over kept ----
  part = 0.0f;
  for (int i = tid; i < L; i += 1024)
    if (s_keep[i]) part += s_e2[i];
#pragma unroll
  for (int d = 32; d > 0; d >>= 1) part += __shfl_xor(part, d);
  if (lane == 0) s_wredf[wid] = part;
  bar_lds();
  if (tid == 0) {
    float s = 0.0f;
    for (int i = 0; i < 16; ++i) s += s_wredf[i];
    s_dn2 = s;
  }
  bar_lds();
  const float denom2 = s_dn2;

  for (int i = tid; i < L; i += 1024)
    s_e2[i] = s_keep[i] ? (s_e2[i] / denom2) : 0.0f;
  __syncthreads();   // FULL drain: zero-stores complete before scatter

  // ---- Gumbel argmax over kept survivors ----
  float bs = -INFINITY;
  int bi = 0x7FFFFFFF;
  for (int i = tid; i < L; i += 1024) {
    if (!s_keep[i]) continue;
    unsigned long long kv = s_skey[p0 + i];
    int j = (int)(kv & 0xFFFFFFFFull);
    float x = ikey((unsigned int)(kv >> 32));
    unsigned int t = (unsigned int)(row * V) + (unsigned int)j;
    unsigned int bb = tf_bits(t);
    float u = __uint_as_float((bb >> 9) | 0x3f800000u) - 1.0f;
    if (u < TINYF) u = TINYF;
    float g = -logf(-logf(u));
    float sc = x + g;
    if (sc > bs || (sc == bs && j < bi)) { bs = sc; bi = j; }
  }

  // ---- scatter nonzero probs (zeros drained above) ----
  for (int i = tid; i < L; i += 1024) {
    int j = (int)(s_skey[p0 + i] & 0xFFFFFFFFull);
    prow[j] = s_e2[i];
  }

  // ---- argmax reduce -> sampled id ----
#pragma unroll
  for (int d = 32; d > 0; d >>= 1) {
    float ov = __shfl_down(bs, d);
    int oi = __shfl_down(bi, d);
    if (ov > bs || (ov == bs && oi < bi)) { bs = ov; bi = oi; }
  }
  if (lane == 0) { s_wredf[wid] = bs; s_wredi[wid] = bi; }
  bar_lds();
  if (tid == 0) {
    float bb = s_wredf[0];
    int bj = s_wredi[0];
    for (int i = 1; i < 16; ++i) {
      if (s_wredf[i] > bb || (s_wredf[i] == bb && s_wredi[i] < bj)) {
        bb = s_wredf[i];
        bj = s_wredi[i];
      }
    }
    out_ids[row] = (float)bj;
  }
}

// ================== Fallback: monolithic kernel (ws too small) ==================
__global__ __launch_bounds__(1024, 1) void sampler_mono(
    const float* __restrict__ logits, const int* __restrict__ toks,
    const float* __restrict__ temps, const float* __restrict__ topps,
    const int* __restrict__ topks, const float* __restrict__ rps,
    float* __restrict__ out_ids, float* __restrict__ probs) {
  __shared__ unsigned int s_seen[VW];
  __shared__ int s_hist[4096];
  __shared__ unsigned short s_cmax16[NCHUNK];
  __shared__ float s_sval[CAPM];
  __shared__ int s_sidx[CAPM];
  __shared__ float s_e[CAPM];
  __shared__ unsigned char s_keep[CAPM];
  __shared__ float s_wredf[16];
  __shared__ int s_wredi[16];
  __shared__ float s_m, s_denom, s_denom2;
  __shared__ int s_b0, s_cnt, s_p0;

  const int row = blockIdx.x;
  const int tid = threadIdx.x;
  const int lane = tid & 63;
  const int wid = tid >> 6;
  const float rp = rps[row];
  const float irp = 1.0f / rp;
  const float itemp = 1.0f / temps[row];
  const float topp = topps[row];
  const int k = topks[row];
  const size_t base = (size_t)row * V;
  const float4* __restrict__ lg4 = reinterpret_cast<const float4*>(logits + base);
  vfloat4* __restrict__ pr4 = reinterpret_cast<vfloat4*>(probs + base);

  for (int i = tid; i < VW; i += 1024) s_seen[i] = 0u;
  for (int i = tid; i < 4096; i += 1024) s_hist[i] = 0;
  __syncthreads();
  for (int i = tid; i < W; i += 1024) {
    int tok = toks[row * W + i];
    if (tok >= 0 && tok < V) atomicOr(&s_seen[tok >> 5], 1u << (tok & 31));
  }
  __syncthreads();

  float lmax = -INFINITY;
  for (int qb = 0; qb < V4; qb += 1024) {
    const int q = qb + tid;
    unsigned int kmax = 0u;
    if (q < V4) {
      float4 x4 = lg4[q];
      float xs[4] = {x4.x, x4.y, x4.z, x4.w};
      const int j0 = q * 4;
      const int sh = j0 & 31;
      unsigned long long ww = (unsigned long long)s_seen[j0 >> 5] |
                              ((unsigned long long)s_seen[(j0 + 3) >> 5] << 32);
#pragma unroll
      for (int e = 0; e < 4; ++e) {
        float x = xform(xs[e], (ww >> (sh + e)) & 1ull, rp, irp, itemp);
        lmax = fmaxf(lmax, x);
        unsigned int ky = fkey(x);
        kmax = kmax > ky ? kmax : ky;
      }
    }
    unsigned int o;
    o = __shfl_xor(kmax, 1); kmax = kmax > o ? kmax : o;
    o = __shfl_xor(kmax, 2); kmax = kmax > o ? kmax : o;
    if (((lane & 3) == 0) && (q < V4)) s_cmax16[q >> 2] = (unsigned short)(kmax >> 16);
  }
#pragma unroll
  for (int d = 32; d > 0; d >>= 1) lmax = fmaxf(lmax, __shfl_xor(lmax, d));
  if (lane == 0) s_wredf[wid] = lmax;
  __syncthreads();
  for (int i = tid; i < NCHUNK; i += 1024)
    atomicAdd(&s_hist[s_cmax16[i] >> 4], 1);
  __syncthreads();
  if (wid == 1 && lane == 0) {
    float mm = s_wredf[0];
    for (int i = 1; i < 16; ++i) mm = fmaxf(mm, s_wredf[i]);
    s_m = mm;
  }
  if (wid == 0) {
    int sm = 0;
    const int bb = lane * 64;
    for (int i = 0; i < 64; ++i) sm += s_hist[bb + i];
    int sfx = sm;
#pragma unroll
    for (int d = 1; d < 64; d <<= 1) {
      int t = __shfl_down(sfx, d);
      if (lane + d < 64) sfx += t;
    }
    unsigned long long mk = __ballot(sfx >= k);
    const int cstar = 63 - __builtin_clzll(mk);
    const int above = __shfl(sfx, cstar) - __shfl(sm, cstar);
    int h = s_hist[cstar * 64 + lane];
    int sfx2 = h;
#pragma unroll
    for (int d = 1; d < 64; d <<= 1) {
      int t = __shfl_down(sfx2, d);
      if (lane + d < 64) sfx2 += t;
    }
    unsigned long long mk2 = __ballot(above + sfx2 >= k);
    const int boff = 63 - __builtin_clzll(mk2);
    if (lane == 0) { s_b0 = cstar * 64 + boff; s_cnt = 0; }
  }
  __syncthreads();
  const int b0 = s_b0;
  const unsigned int fk0 = ((unsigned int)b0) << 20;
  const int c16 = b0 << 4;
  for (int qb = 0; qb < V4; qb += 1024) {
    const int q = qb + tid;
    const bool act = (q < V4) && ((int)s_cmax16[q >> 2] >= c16);
    float xs[4];
    bool pr[4] = {false, false, false, false};
    const int j0 = q * 4;
    if (act) {
      float4 x4 = lg4[q];
      float raw[4] = {x4.x, x4.y, x4.z, x4.w};
      const int sh = j0 & 31;
      unsigned long long ww = (unsigned long long)s_seen[j0 >> 5] |
                              ((unsigned long long)s_seen[(j0 + 3) >> 5] << 32);
#pragma unroll
      for (int e = 0; e < 4; ++e) {
        xs[e] = xform(raw[e], (ww >> (sh + e)) & 1ull, rp, irp, itemp);
        pr[e] = (fkey(xs[e]) >= fk0);
      }
    }
#pragma unroll
    for (int e = 0; e < 4; ++e) {
      unsigned long long mask = __ballot(pr[e]);
      if (!mask) continue;
      int basep = 0;
      if (lane == 0) basep = atomicAdd(&s_cnt, __popcll(mask));
      basep = __shfl(basep, 0);
      if (pr[e]) {
        int pos = basep + __popcll(mask & ((1ull << lane) - 1ull));
        if (pos < CAPM) { s_sval[pos] = xs[e]; s_sidx[pos] = j0 + e; }
      }
    }
  }
  __syncthreads();
  int G = s_cnt;
  if (G > CAPM) G = CAPM;
  int np2 = 2;
  while (np2 < G) np2 <<= 1;
  for (int i = G + tid; i < np2; i += 1024) {
    s_sval[i] = INFINITY;
    s_sidx[i] = 0x7FFFFFFF;
  }
  __syncthreads();
  for (int size = 2; size <= np2; size <<= 1) {
    for (int stride = size >> 1; stride > 0; stride >>= 1) {
      for (int t2 = tid; t2 < (np2 >> 1); t2 += 1024) {
        int pos = 2 * t2 - (t2 & (stride - 1));
        int qq = pos + stride;
        bool up = ((pos & size) == 0);
        float v1 = s_sval[pos], v2 = s_sval[qq];
        int i1 = s_sidx[pos], i2 = s_sidx[qq];
        bool gt = (v1 > v2) || (v1 == v2 && i1 > i2);
        if (gt == up) {
          s_sval[pos] = v2; s_sval[qq] = v1;
          s_sidx[pos] = i2; s_sidx[qq] = i1;
        }
      }
      __syncthreads();
    }
  }
  const int kk = k > G ? G : k;
  const float kth = s_sval[G - kk];
  const float m = s_m;
  for (int i = tid; i < G; i += 1024) {
    if (s_sval[i] >= kth && (i == 0 || s_sval[i - 1] < kth)) s_p0 = i;
  }
  __syncthreads();
  const int p0 = s_p0;
  float part = 0.0f;
  for (int i = p0 + tid; i < G; i += 1024) {
    float e = expf(s_sval[i] - m);
    s_e[i] = e;
    part += e;
  }
#pragma unroll
  for (int d = 32; d > 0; d >>= 1) part += __shfl_xor(part, d);
  if (lane == 0) s_wredf[wid] = part;
  __syncthreads();
  if (tid == 0) {
    float s = 0.0f;
    for (int i = 0; i < 16; ++i) s += s_wredf[i];
    s_denom = s;
  }
  __syncthreads();
  const float denom = s_denom;
  if (tid == 0) {
    const float cut = 1.0f - topp;
    float cs = 0.0f;
    for (int i = p0; i < G; ++i) {
      cs += s_e[i] / denom;
      s_keep[i] = (cs <= cut) ? 0 : 1;
    }
    s_keep[G - 1] = 1;
  }
  __syncthreads();
  part = 0.0f;
  for (int i = p0 + tid; i < G; i += 1024)
    if (s_keep[i]) part += s_e[i];
#pragma unroll
  for (int d = 32; d > 0; d >>= 1) part += __shfl_xor(part, d);
  if (lane == 0) s_wredf[wid] = part;
  __syncthreads();
  if (tid == 0) {
    float s = 0.0f;
    for (int i = 0; i < 16; ++i) s += s_wredf[i];
    s_denom2 = s;
  }
  __syncthreads();
  const float denom2 = s_denom2;
  for (int i = p0 + tid; i < G; i += 1024)
    s_e[i] = s_keep[i] ? (s_e[i] / denom2) : 0.0f;
  __syncthreads();
  float bs = -INFINITY;
  int bi = 0x7FFFFFFF;
  for (int i = p0 + tid; i < G; i += 1024) {
    if (!s_keep[i]) continue;
    int j = s_sidx[i];
    unsigned int t = (unsigned int)(row * V) + (unsigned int)j;
    unsigned int bb = tf_bits(t);
    float u = __uint_as_float((bb >> 9) | 0x3f800000u) - 1.0f;
    if (u < TINYF) u = TINYF;
    float g = -logf(-logf(u));
    float sc = s_sval[i] + g;
    if (sc > bs || (sc == bs && j < bi)) { bs = sc; bi = j; }
  }
  const unsigned int kkey = fkey(kth);
  const int k16 = (int)(kkey >> 16);
  for (int q = tid; q < V4; q += 1024) {
    vfloat4 o = (vfloat4){0.0f, 0.0f, 0.0f, 0.0f};
    if ((int)s_cmax16[q >> 2] >= k16) {
      float4 x4 = lg4[q];
      float raw[4] = {x4.x, x4.y, x4.z, x4.w};
      float os[4];
      const int j0 = q * 4;
      const int sh = j0 & 31;
      unsigned long long ww = (unsigned long long)s_seen[j0 >> 5] |
                              ((unsigned long long)s_seen[(j0 + 3) >> 5] << 32);
#pragma unroll
      for (int e = 0; e < 4; ++e) {
        float x = xform(raw[e], (ww >> (sh + e)) & 1ull, rp, irp, itemp);
        float pr = 0.0f;
        if (x >= kth) {
          int j = j0 + e;
          int lo = p0, hi = G;
          while (lo < hi) {
            int mid = (lo + hi) >> 1;
            float v = s_sval[mid];
            int id = s_sidx[mid];
            if (v < x || (v == x && id < j)) lo = mid + 1; else hi = mid;
          }
          pr = s_e[lo];
        }
        os[e] = pr;
      }
      o.x = os[0]; o.y = os[1]; o.z = os[2]; o.w = os[3];
    }
    pr4[q] = o;
  }
#pragma unroll
  for (int d = 32; d > 0; d >>= 1) {
    float ov = __shfl_down(bs, d);
    int oi = __shfl_down(bi, d);
    if (ov > bs || (ov == bs && oi < bi)) { bs = ov; bi = oi; }
  }
  if (lane == 0) { s_wredf[wid] = bs; s_wredi[wid] = bi; }
  __syncthreads();
  if (tid == 0) {
    float bb = s_wredf[0];
    int bj = s_wredi[0];
    for (int i = 1; i < 16; ++i) {
      if (s_wredf[i] > bb || (s_wredf[i] == bb && s_wredi[i] < bj)) {
        bb = s_wredf[i];
        bj = s_wredi[i];
      }
    }
    out_ids[row] = (float)bj;
  }
}

extern "C" void kernel_launch(void* const* d_in, const int* in_sizes, int n_in,
                              void* d_out, int out_size, void* d_ws, size_t ws_size,
                              hipStream_t stream) {
  (void)in_sizes; (void)out_size;
  if (n_in < 6) return;
  const float* logits = (const float*)d_in[0];
  const int* toks = (const int*)d_in[1];
  const float* temps = (const float*)d_in[2];
  const float* topps = (const float*)d_in[3];
  const int* topks = (const int*)d_in[4];
  const float* rps = (const float*)d_in[5];
  float* out = (float*)d_out;            // [0,256): ids as float; [256,...): probs
  float* probs = out + NROWS;

  if (ws_size >= WS_NEED && d_ws != nullptr) {
    char* w = (char*)d_ws;
    unsigned short* ws_cmax = (unsigned short*)(w + WS_CMAX);
    float* ws_bmax = (float*)(w + WS_BMAX);
    kA_chunkmax<<<dim3(NROWS * NSLICE), dim3(256), 0, stream>>>(
        logits, toks, temps, rps, ws_cmax, ws_bmax);
    kB_select<<<dim3(NROWS), dim3(1024), 0, stream>>>(
        logits, toks, temps, topps, topks, rps, ws_cmax, ws_bmax, out, probs);
  } else {
    sampler_mono<<<dim3(NROWS), dim3(1024), 0, stream>>>(
        logits, toks, temps, topps, topks, rps, out, probs);
  }
}